// Round 3
// baseline (661.784 us; speedup 1.0000x reference)
//
#include <hip/hip_runtime.h>
#include <cstdint>

#define H 2048
#define NH 16
#define QLR 1536
#define KVLR 512
#define NOPE 128
#define ROPED 64
#define VH 128
#define QHD 192
#define SEQ 2048
#define NQH (NH*QHD)        // 3072
#define NKVC (NH*(NOPE+VH)) // 4096
#define NOV (NH*VH)         // 2048
#define KVAW_N (KVLR+ROPED) // 576
#define SCALE_L2E 0.10411755f   // 192^-0.5 * log2(e)
#define NSEG 4

typedef __attribute__((ext_vector_type(8))) short short8;
typedef __attribute__((ext_vector_type(4))) short short4v;
typedef __attribute__((ext_vector_type(4))) float floatx4;

__device__ __forceinline__ short f2bf(float x) {
  unsigned u = __builtin_bit_cast(unsigned, x);
  unsigned r = (u + 0x7FFFu + ((u >> 16) & 1u)) >> 16;
  return (short)(unsigned short)r;
}
__device__ __forceinline__ float bf2f(short s) {
  unsigned u = ((unsigned)(unsigned short)s) << 16;
  return __builtin_bit_cast(float, u);
}
__device__ __forceinline__ void g2l16(const void* g, void* l) {
  __builtin_amdgcn_global_load_lds(
      (const __attribute__((address_space(1))) void*)(uintptr_t)(g),
      (__attribute__((address_space(3))) void*)(uintptr_t)(l),
      16, 0, 0);
}

// ---------------- fp32 -> bf16 convert ----------------
__global__ __launch_bounds__(256) void k_cvt_bf16(const float* __restrict__ x,
                                                  short* __restrict__ y, int n4) {
  int i = blockIdx.x * 256 + threadIdx.x;
  if (i >= n4) return;
  float4 v = ((const float4*)x)[i];
  short4v o;
  o.x = f2bf(v.x); o.y = f2bf(v.y); o.z = f2bf(v.z); o.w = f2bf(v.w);
  ((short4v*)y)[i] = o;
}

// ---------------- NT GEMM: C[M,N] = A[M,K]*B[N,K]^T ----------------
template<int MODE>
__global__ __launch_bounds__(256) void k_gemm_nt(
    const short* __restrict__ A, const short* __restrict__ B,
    void* __restrict__ C, short* __restrict__ C2, int M, int N, int K)
{
  __shared__ short As[4*128*8];
  __shared__ short Bs[4*128*8];
  const int tid = threadIdx.x;
  const int lane = tid & 63;
  const int w = tid >> 6;
  const int wm = w & 1, wn = w >> 1;
  const int quad = lane >> 4, l16 = lane & 15;
  const int m0 = blockIdx.x * 128, n0 = blockIdx.y * 128;

  floatx4 acc[4][4] = {};

  for (int k0 = 0; k0 < K; k0 += 32) {
    __syncthreads();
#pragma unroll
    for (int i = 0; i < 2; ++i) {
      int c = i*256 + tid;
      int row = c & 127, koct = c >> 7;
      g2l16(A + (size_t)(m0 + row)*K + k0 + koct*8, As + (size_t)(i*256 + w*64)*8);
      int nrow = n0 + row; nrow = (nrow < N) ? nrow : (N-1);
      g2l16(B + (size_t)nrow*K + k0 + koct*8,      Bs + (size_t)(i*256 + w*64)*8);
    }
    __syncthreads();
    short8 af[4], bfr[4];
#pragma unroll
    for (int mi = 0; mi < 4; ++mi)
      af[mi] = *(const short8*)(As + (quad*128 + wm*64 + mi*16 + l16)*8);
#pragma unroll
    for (int ni = 0; ni < 4; ++ni)
      bfr[ni] = *(const short8*)(Bs + (quad*128 + wn*64 + ni*16 + l16)*8);
#pragma unroll
    for (int mi = 0; mi < 4; ++mi)
#pragma unroll
      for (int ni = 0; ni < 4; ++ni)
        acc[mi][ni] = __builtin_amdgcn_mfma_f32_16x16x32_bf16(af[mi], bfr[ni], acc[mi][ni], 0, 0, 0);
  }

  if (MODE == 2 && (n0 & 128)) {
#pragma unroll
    for (int mi = 0; mi < 4; ++mi) {
#pragma unroll
      for (int ni = 0; ni < 4; ++ni) {
        int col = n0 + wn*64 + ni*16 + l16;
        int h = col >> 8, dv = (col & 255) - 128;
        int row = m0 + wm*64 + mi*16 + quad*4;
        short4v pk;
        pk.x = f2bf(acc[mi][ni][0]); pk.y = f2bf(acc[mi][ni][1]);
        pk.z = f2bf(acc[mi][ni][2]); pk.w = f2bf(acc[mi][ni][3]);
        *(short4v*)(C2 + (size_t)(h*128 + dv)*SEQ + row) = pk;
      }
    }
    return;
  }

#pragma unroll
  for (int mi = 0; mi < 4; ++mi) {
#pragma unroll
    for (int ni = 0; ni < 4; ++ni) {
      int col = n0 + wn*64 + ni*16 + l16;
      if (col < N) {
#pragma unroll
        for (int r = 0; r < 4; ++r) {
          int row = m0 + wm*64 + mi*16 + quad*4 + r;
          if (MODE == 0)
            ((float*)C)[(size_t)row*N + col] = acc[mi][ni][r];
          else
            ((short*)C)[(size_t)row*N + col] = f2bf(acc[mi][ni][r]);
        }
      }
    }
  }
}

// ---------------- RMS norm (row-wise, fp32 -> bf16) ----------------
__global__ __launch_bounds__(256) void k_rmsnorm(
    const float* __restrict__ x, int xstride,
    const float* __restrict__ w, short* __restrict__ y, int L)
{
  int row = blockIdx.x;
  const float* xr = x + (size_t)row * xstride;
  float s = 0.f;
  for (int i = threadIdx.x; i < L; i += 256) { float v = xr[i]; s += v*v; }
#pragma unroll
  for (int off = 1; off < 64; off <<= 1) s += __shfl_xor(s, off);
  __shared__ float red[4];
  if ((threadIdx.x & 63) == 0) red[threadIdx.x >> 6] = s;
  __syncthreads();
  float tot = red[0] + red[1] + red[2] + red[3];
  float inv = rsqrtf(tot / (float)L + 1e-6f);
  for (int i = threadIdx.x; i < L; i += 256)
    y[(size_t)row * L + i] = f2bf(xr[i] * inv * w[i]);
}

// ---------------- RoPE+prescale on q (bf16 in -> bf16 out) ----------------
__global__ __launch_bounds__(256) void k_rope_q(const short* __restrict__ q,
                                                short* __restrict__ qb) {
  int row = blockIdx.y;
  int t2 = blockIdx.x * 256 + threadIdx.x;  // 0..2559
  int h = t2 / 160, d = t2 - h * 160;
  const short* src = q + (size_t)row * NQH + h * QHD;
  short* dst = qb + (size_t)row * NQH + h * QHD;
  if (d < 128) {
    dst[d] = f2bf(bf2f(src[d]) * SCALE_L2E);
  } else {
    int i = d - 128;                        // 0..31
    float ang = (float)row * powf(10000.0f, -(float)i / 32.0f);
    float c = cosf(ang), s = sinf(ang);
    float x1 = bf2f(src[128 + i]), x2 = bf2f(src[160 + i]);
    dst[128 + i] = f2bf((x1 * c - x2 * s) * SCALE_L2E);
    dst[160 + i] = f2bf((x2 * c + x1 * s) * SCALE_L2E);
  }
}

// ---------------- RoPE on k_pe (fp32 in, NOT scaled) ----------------
__global__ __launch_bounds__(256) void k_rope_k(const float* __restrict__ kvlp,
                                                short* __restrict__ kpe) {
  int idx = blockIdx.x * 256 + threadIdx.x;  // SEQ*32
  int row = idx >> 5, i = idx & 31;
  const float* src = kvlp + (size_t)row * KVAW_N + KVLR;
  float ang = (float)row * powf(10000.0f, -(float)i / 32.0f);
  float c = cosf(ang), s = sinf(ang);
  float x1 = src[i], x2 = src[i + 32];
  kpe[(size_t)row * ROPED + i]      = f2bf(x1 * c - x2 * s);
  kpe[(size_t)row * ROPED + i + 32] = f2bf(x2 * c + x1 * s);
}

// ---------------- split-KV causal flash attention ----------------
// grid (NSEG, 16, NH), block 256 = 4 waves. q-tile 128 rows, wave owns 32.
// Segment s covers kv chunks [s*8, min(nch, s*8+8)), chunk = 64 kv.
// Writes normalized partial O (bf16) + (m,l) per (seg,q,h).
__global__ __launch_bounds__(256) void k_attn3(
    const short* __restrict__ qb,   // [SEQ][NQH] prescaled by SCALE_L2E
    const short* __restrict__ kvb,  // [SEQ][NKVC] (K-nope half valid)
    const short* __restrict__ kpe,  // [SEQ][ROPED]
    const short* __restrict__ vT,   // [NH*128][SEQ]
    short* __restrict__ Opart,      // [NSEG][SEQ][NOV]
    float2* __restrict__ mlb)       // [NSEG][SEQ][NH]
{
  __shared__ short Kl[64 * 200];
  __shared__ short Vl[128 * 72];
  __shared__ short Pl[4 * 32 * 72];
  const int tid = threadIdx.x;
  const int lane = tid & 63, w = tid >> 6;
  const int quad = lane >> 4, l16 = lane & 15;
  const int sgi = blockIdx.x;
  const int qt = 15 - (int)blockIdx.y;   // long tiles first
  const int h = blockIdx.z;
  const int q0 = qt * 128;
  const int nch = 2 * qt + 2;
  const int cs = sgi * 8, ce = (nch < cs + 8) ? nch : (cs + 8);
  if (cs >= ce) return;
  const int qw = q0 + w * 32;
  short* Plw = Pl + w * (32 * 72);

  short8 qf[2][6];
#pragma unroll
  for (int nt = 0; nt < 2; ++nt)
#pragma unroll
    for (int ks = 0; ks < 6; ++ks)
      qf[nt][ks] = *(const short8*)(qb + (size_t)(qw + nt*16 + l16) * NQH
                                    + h * QHD + ks * 32 + quad * 8);

  floatx4 oacc[8][2] = {};
  float m_i[2] = {-1e30f, -1e30f}, l_i[2] = {0.f, 0.f};

  for (int kc = cs; kc < ce; ++kc) {
    const int kv0 = kc * 64;
    __syncthreads();
    // stage K-nope: 64 rows x 16 octets
#pragma unroll
    for (int i = 0; i < 4; ++i) {
      int c = i * 256 + tid;
      int row = c >> 4, oct = c & 15;
      *(short8*)(Kl + row * 200 + oct * 8) =
          *(const short8*)(kvb + (size_t)(kv0 + row) * NKVC + h * 256 + oct * 8);
    }
    // stage K-rope: 64 rows x 8 octets
#pragma unroll
    for (int i = 0; i < 2; ++i) {
      int c = i * 256 + tid;
      int row = c >> 3, oct = c & 7;
      *(short8*)(Kl + row * 200 + 128 + oct * 8) =
          *(const short8*)(kpe + (size_t)(kv0 + row) * ROPED + oct * 8);
    }
    // stage V^T: 128 d rows x 8 kv-octets
#pragma unroll
    for (int i = 0; i < 4; ++i) {
      int c = i * 256 + tid;
      int d = c >> 3, ck = c & 7;
      *(short8*)(Vl + d * 72 + ck * 8) =
          *(const short8*)(vT + (size_t)(h * 128 + d) * SEQ + kv0 + ck * 8);
    }
    __syncthreads();
    if (kv0 >= qw + 32) continue;  // chunk fully masked for this wave

    floatx4 s[4][2] = {};
#pragma unroll
    for (int ks = 0; ks < 6; ++ks) {
#pragma unroll
      for (int mt = 0; mt < 4; ++mt) {
        short8 kf = *(const short8*)(Kl + (mt*16 + l16) * 200 + ks * 32 + quad * 8);
#pragma unroll
        for (int nt = 0; nt < 2; ++nt)
          s[mt][nt] = __builtin_amdgcn_mfma_f32_16x16x32_bf16(kf, qf[nt][ks], s[mt][nt], 0, 0, 0);
      }
    }

    const bool diag = (kv0 + 64 > qw);
#pragma unroll
    for (int nt = 0; nt < 2; ++nt) {
      const int qg = qw + nt * 16 + l16;
      float mx = -1e30f;
#pragma unroll
      for (int mt = 0; mt < 4; ++mt) {
#pragma unroll
        for (int r = 0; r < 4; ++r) {
          float v = s[mt][nt][r];
          if (diag) {
            int kvg = kv0 + mt * 16 + quad * 4 + r;
            v = (kvg <= qg) ? v : -1e30f;
            s[mt][nt][r] = v;
          }
          mx = fmaxf(mx, v);
        }
      }
      mx = fmaxf(mx, __shfl_xor(mx, 16));
      mx = fmaxf(mx, __shfl_xor(mx, 32));
      float mnew = fmaxf(m_i[nt], mx);
      float alpha = exp2f(m_i[nt] - mnew);
      m_i[nt] = mnew;
      float ssum = 0.f;
#pragma unroll
      for (int mt = 0; mt < 4; ++mt) {
        float p0 = exp2f(s[mt][nt][0] - mnew);
        float p1 = exp2f(s[mt][nt][1] - mnew);
        float p2 = exp2f(s[mt][nt][2] - mnew);
        float p3 = exp2f(s[mt][nt][3] - mnew);
        ssum += (p0 + p1) + (p2 + p3);
        short4v pk; pk.x = f2bf(p0); pk.y = f2bf(p1); pk.z = f2bf(p2); pk.w = f2bf(p3);
        *(short4v*)(Plw + (nt*16 + l16) * 72 + mt * 16 + quad * 4) = pk;
      }
      ssum += __shfl_xor(ssum, 16);
      ssum += __shfl_xor(ssum, 32);
      l_i[nt] = l_i[nt] * alpha + ssum;
#pragma unroll
      for (int dt = 0; dt < 8; ++dt)
#pragma unroll
        for (int r = 0; r < 4; ++r) oacc[dt][nt][r] *= alpha;
    }

#pragma unroll
    for (int kc2 = 0; kc2 < 2; ++kc2) {
      short8 pf[2];
#pragma unroll
      for (int nt = 0; nt < 2; ++nt)
        pf[nt] = *(const short8*)(Plw + (nt*16 + l16) * 72 + kc2 * 32 + quad * 8);
#pragma unroll
      for (int dt = 0; dt < 8; ++dt) {
        short8 vf = *(const short8*)(Vl + (dt*16 + l16) * 72 + kc2 * 32 + quad * 8);
#pragma unroll
        for (int nt = 0; nt < 2; ++nt)
          oacc[dt][nt] = __builtin_amdgcn_mfma_f32_16x16x32_bf16(vf, pf[nt], oacc[dt][nt], 0, 0, 0);
      }
    }
  }

  // epilogue: store normalized partial + (m,l)
#pragma unroll
  for (int nt = 0; nt < 2; ++nt) {
    float inv = 1.f / l_i[nt];
    int q = qw + nt * 16 + l16;
    if (quad == 0)
      mlb[((size_t)sgi * SEQ + q) * NH + h] = make_float2(m_i[nt], l_i[nt]);
#pragma unroll
    for (int dt = 0; dt < 8; ++dt) {
      short4v pk;
      pk.x = f2bf(oacc[dt][nt][0] * inv);
      pk.y = f2bf(oacc[dt][nt][1] * inv);
      pk.z = f2bf(oacc[dt][nt][2] * inv);
      pk.w = f2bf(oacc[dt][nt][3] * inv);
      *(short4v*)(Opart + ((size_t)sgi * SEQ + q) * NOV + h * VH + dt * 16 + quad * 4) = pk;
    }
  }
}

// ---------------- split-KV combiner ----------------
__global__ __launch_bounds__(256) void k_comb(
    const short* __restrict__ Opart, const float2* __restrict__ mlb,
    short* __restrict__ ob)
{
  int q = blockIdx.x;
  int hd0 = threadIdx.x * 8;
  int h = hd0 >> 7;
  int nact = (q >> 9) + 1;
  float2 mlv[NSEG];
  float M = -1e30f;
  for (int s = 0; s < nact; ++s) {
    mlv[s] = mlb[((size_t)s * SEQ + q) * NH + h];
    M = fmaxf(M, mlv[s].x);
  }
  float wgt[NSEG]; float L = 0.f;
  for (int s = 0; s < nact; ++s) {
    wgt[s] = mlv[s].y * exp2f(mlv[s].x - M);
    L += wgt[s];
  }
  float invL = 1.0f / L;
  float acc[8] = {};
  for (int s = 0; s < nact; ++s) {
    short8 o = *(const short8*)(Opart + ((size_t)s * SEQ + q) * NOV + hd0);
    float ws = wgt[s] * invL;
#pragma unroll
    for (int j = 0; j < 8; ++j) acc[j] += ws * bf2f(o[j]);
  }
  short8 r;
#pragma unroll
  for (int j = 0; j < 8; ++j) r[j] = f2bf(acc[j]);
  *(short8*)(ob + (size_t)q * NOV + hd0) = r;
}

// ---------------- launch ----------------
extern "C" void kernel_launch(void* const* d_in, const int* in_sizes, int n_in,
                              void* d_out, int out_size, void* d_ws, size_t ws_size,
                              hipStream_t stream) {
  const float* hs      = (const float*)d_in[0];
  const float* q_a_w   = (const float*)d_in[1];
  const float* q_a_ln  = (const float*)d_in[2];
  const float* q_b_w   = (const float*)d_in[3];
  const float* kv_a_w  = (const float*)d_in[4];
  const float* kv_a_ln = (const float*)d_in[5];
  const float* kv_b_w  = (const float*)d_in[6];
  const float* o_w     = (const float*)d_in[7];
  float* out = (float*)d_out;

  char* ws = (char*)d_ws;
  size_t off = 0;
  auto alloc = [&](size_t bytes) {
    void* p = ws + off;
    off += (bytes + 255) & ~(size_t)255;
    return p;
  };
  const size_t MB = 1u << 20;
  // static buffers
  short* hs_b   = (short*)alloc((size_t)SEQ * H * 2);
  short* qaw_b  = (short*)alloc((size_t)QLR * H * 2);
  short* qbw_b  = (short*)alloc((size_t)NQH * QLR * 2);
  short* kvaw_b = (short*)alloc((size_t)KVAW_N * H * 2);
  short* kvbw_b = (short*)alloc((size_t)NKVC * KVLR * 2);
  short* ow_b   = (short*)alloc((size_t)H * NOV * 2);
  short* qbf    = (short*)alloc((size_t)SEQ * NQH * 2);
  short* kpeb   = (short*)alloc((size_t)SEQ * ROPED * 2);
  short* kvbuf  = (short*)alloc((size_t)SEQ * NKVC * 2);
  short* vT     = (short*)alloc((size_t)NH * VH * SEQ * 2);
  short* attnb  = (short*)alloc((size_t)SEQ * NOV * 2);
  // overlay region (36 MB): phase-disjoint temporaries
  char* R = (char*)alloc(36 * MB);
  float* qlat  = (float*)R;                 // [SEQ][QLR] fp32   (phase 1)
  short* qlatn = (short*)(R + 13 * MB);     // [SEQ][QLR] bf16   (phase 1-2)
  short* qtmp  = (short*)R;                 // [SEQ][NQH] bf16   (phase 2, aliases dead qlat)
  float* kvlp  = (float*)R;                 // [SEQ][KVAW_N] fp32 (phase 3, aliases dead qtmp)
  short* kvln  = (short*)(R + 20 * MB);     // [SEQ][KVLR] bf16  (phase 3-4)
  short* Opart = (short*)R;                 // [NSEG][SEQ][NOV] bf16 (attn phase, 33.6MB)
  float2* mlb  = (float2*)(R + 34 * MB);    // [NSEG][SEQ][NH]   (attn phase)

  auto cvt = [&](const float* x, short* y, size_t n) {
    int n4 = (int)(n / 4);
    k_cvt_bf16<<<dim3((n4 + 255) / 256), 256, 0, stream>>>(x, y, n4);
  };
  cvt(hs,     hs_b,   (size_t)SEQ * H);
  cvt(q_a_w,  qaw_b,  (size_t)QLR * H);
  cvt(q_b_w,  qbw_b,  (size_t)NQH * QLR);
  cvt(kv_a_w, kvaw_b, (size_t)KVAW_N * H);
  cvt(kv_b_w, kvbw_b, (size_t)NKVC * KVLR);
  cvt(o_w,    ow_b,   (size_t)H * NOV);

  // q_lat = hs @ q_a_w^T (fp32)
  k_gemm_nt<0><<<dim3(SEQ/128, QLR/128), 256, 0, stream>>>(hs_b, qaw_b, qlat, nullptr, SEQ, QLR, H);
  k_rmsnorm<<<SEQ, 256, 0, stream>>>(qlat, QLR, q_a_ln, qlatn, QLR);
  // q = q_lat_n @ q_b_w^T (bf16)
  k_gemm_nt<1><<<dim3(SEQ/128, NQH/128), 256, 0, stream>>>(qlatn, qbw_b, qtmp, nullptr, SEQ, NQH, QLR);
  k_rope_q<<<dim3(10, SEQ), 256, 0, stream>>>(qtmp, qbf);
  // kv_lat_pe = hs @ kv_a_w^T (fp32)
  k_gemm_nt<0><<<dim3(SEQ/128, (KVAW_N+127)/128), 256, 0, stream>>>(hs_b, kvaw_b, kvlp, nullptr, SEQ, KVAW_N, H);
  k_rmsnorm<<<SEQ, 256, 0, stream>>>(kvlp, KVAW_N, kv_a_ln, kvln, KVLR);
  k_rope_k<<<(SEQ*32)/256, 256, 0, stream>>>(kvlp, kpeb);
  // kv = kv_lat_n @ kv_b_w^T : K half -> kvbuf, V half -> vT (transposed)
  k_gemm_nt<2><<<dim3(SEQ/128, NKVC/128), 256, 0, stream>>>(kvln, kvbw_b, kvbuf, vT, SEQ, NKVC, KVLR);
  // split-KV attention + combine
  k_attn3<<<dim3(NSEG, 16, NH), 256, 0, stream>>>(qbf, kvbuf, kpeb, vT, Opart, mlb);
  k_comb<<<SEQ, 256, 0, stream>>>(Opart, mlb, attnb);
  // out = attn @ o_w^T (fp32)
  k_gemm_nt<0><<<dim3(SEQ/128, H/128), 256, 0, stream>>>(attnb, ow_b, out, nullptr, SEQ, H, NOV);
}

// Round 4
// 650.101 us; speedup vs baseline: 1.0180x; 1.0180x over previous
//
#include <hip/hip_runtime.h>
#include <cstdint>

#define H 2048
#define NH 16
#define QLR 1536
#define KVLR 512
#define NOPE 128
#define ROPED 64
#define VH 128
#define QHD 192
#define SEQ 2048
#define NQH (NH*QHD)        // 3072
#define NKVC (NH*(NOPE+VH)) // 4096
#define NOV (NH*VH)         // 2048
#define KVAW_N (KVLR+ROPED) // 576
#define SCALE_L2E 0.10411755f   // 192^-0.5 * log2(e)
#define NSEG 4

typedef __attribute__((ext_vector_type(8))) short short8;
typedef __attribute__((ext_vector_type(4))) short short4v;
typedef __attribute__((ext_vector_type(4))) float floatx4;

__device__ __forceinline__ short f2bf(float x) {
  unsigned u = __builtin_bit_cast(unsigned, x);
  unsigned r = (u + 0x7FFFu + ((u >> 16) & 1u)) >> 16;
  return (short)(unsigned short)r;
}
__device__ __forceinline__ float bf2f(short s) {
  unsigned u = ((unsigned)(unsigned short)s) << 16;
  return __builtin_bit_cast(float, u);
}
__device__ __forceinline__ void g2l16(const void* g, void* l) {
  __builtin_amdgcn_global_load_lds(
      (const __attribute__((address_space(1))) void*)(uintptr_t)(g),
      (__attribute__((address_space(3))) void*)(uintptr_t)(l),
      16, 0, 0);
}

// ---------------- fp32 -> bf16 convert ----------------
__global__ __launch_bounds__(256) void k_cvt_bf16(const float* __restrict__ x,
                                                  short* __restrict__ y, int n4) {
  int i = blockIdx.x * 256 + threadIdx.x;
  if (i >= n4) return;
  float4 v = ((const float4*)x)[i];
  short4v o;
  o.x = f2bf(v.x); o.y = f2bf(v.y); o.z = f2bf(v.z); o.w = f2bf(v.w);
  ((short4v*)y)[i] = o;
}

// ---------------- NT GEMM: C[M,N] = A[M,K]*B[N,K]^T ----------------
template<int MODE>
__global__ __launch_bounds__(256) void k_gemm_nt(
    const short* __restrict__ A, const short* __restrict__ B,
    void* __restrict__ C, short* __restrict__ C2, int M, int N, int K)
{
  __shared__ short As[4*128*8];
  __shared__ short Bs[4*128*8];
  const int tid = threadIdx.x;
  const int lane = tid & 63;
  const int w = tid >> 6;
  const int wm = w & 1, wn = w >> 1;
  const int quad = lane >> 4, l16 = lane & 15;
  const int m0 = blockIdx.x * 128, n0 = blockIdx.y * 128;

  floatx4 acc[4][4] = {};

  for (int k0 = 0; k0 < K; k0 += 32) {
    __syncthreads();
#pragma unroll
    for (int i = 0; i < 2; ++i) {
      int c = i*256 + tid;
      int row = c & 127, koct = c >> 7;
      g2l16(A + (size_t)(m0 + row)*K + k0 + koct*8, As + (size_t)(i*256 + w*64)*8);
      int nrow = n0 + row; nrow = (nrow < N) ? nrow : (N-1);
      g2l16(B + (size_t)nrow*K + k0 + koct*8,      Bs + (size_t)(i*256 + w*64)*8);
    }
    __syncthreads();
    short8 af[4], bfr[4];
#pragma unroll
    for (int mi = 0; mi < 4; ++mi)
      af[mi] = *(const short8*)(As + (quad*128 + wm*64 + mi*16 + l16)*8);
#pragma unroll
    for (int ni = 0; ni < 4; ++ni)
      bfr[ni] = *(const short8*)(Bs + (quad*128 + wn*64 + ni*16 + l16)*8);
#pragma unroll
    for (int mi = 0; mi < 4; ++mi)
#pragma unroll
      for (int ni = 0; ni < 4; ++ni)
        acc[mi][ni] = __builtin_amdgcn_mfma_f32_16x16x32_bf16(af[mi], bfr[ni], acc[mi][ni], 0, 0, 0);
  }

  if (MODE == 2 && (n0 & 128)) {
#pragma unroll
    for (int mi = 0; mi < 4; ++mi) {
#pragma unroll
      for (int ni = 0; ni < 4; ++ni) {
        int col = n0 + wn*64 + ni*16 + l16;
        int h = col >> 8, dv = (col & 255) - 128;
        int row = m0 + wm*64 + mi*16 + quad*4;
        short4v pk;
        pk.x = f2bf(acc[mi][ni][0]); pk.y = f2bf(acc[mi][ni][1]);
        pk.z = f2bf(acc[mi][ni][2]); pk.w = f2bf(acc[mi][ni][3]);
        *(short4v*)(C2 + (size_t)(h*128 + dv)*SEQ + row) = pk;
      }
    }
    return;
  }

#pragma unroll
  for (int mi = 0; mi < 4; ++mi) {
#pragma unroll
    for (int ni = 0; ni < 4; ++ni) {
      int col = n0 + wn*64 + ni*16 + l16;
      if (col < N) {
#pragma unroll
        for (int r = 0; r < 4; ++r) {
          int row = m0 + wm*64 + mi*16 + quad*4 + r;
          if (MODE == 0)
            ((float*)C)[(size_t)row*N + col] = acc[mi][ni][r];
          else
            ((short*)C)[(size_t)row*N + col] = f2bf(acc[mi][ni][r]);
        }
      }
    }
  }
}

// ---------------- RMS norm (row-wise, fp32 -> bf16) ----------------
__global__ __launch_bounds__(256) void k_rmsnorm(
    const float* __restrict__ x, int xstride,
    const float* __restrict__ w, short* __restrict__ y, int L)
{
  int row = blockIdx.x;
  const float* xr = x + (size_t)row * xstride;
  float s = 0.f;
  for (int i = threadIdx.x; i < L; i += 256) { float v = xr[i]; s += v*v; }
#pragma unroll
  for (int off = 1; off < 64; off <<= 1) s += __shfl_xor(s, off);
  __shared__ float red[4];
  if ((threadIdx.x & 63) == 0) red[threadIdx.x >> 6] = s;
  __syncthreads();
  float tot = red[0] + red[1] + red[2] + red[3];
  float inv = rsqrtf(tot / (float)L + 1e-6f);
  for (int i = threadIdx.x; i < L; i += 256)
    y[(size_t)row * L + i] = f2bf(xr[i] * inv * w[i]);
}

// ---------------- RoPE+prescale on q (bf16 in -> bf16 out) ----------------
__global__ __launch_bounds__(256) void k_rope_q(const short* __restrict__ q,
                                                short* __restrict__ qb) {
  int row = blockIdx.y;
  int t2 = blockIdx.x * 256 + threadIdx.x;  // 0..2559
  int h = t2 / 160, d = t2 - h * 160;
  const short* src = q + (size_t)row * NQH + h * QHD;
  short* dst = qb + (size_t)row * NQH + h * QHD;
  if (d < 128) {
    dst[d] = f2bf(bf2f(src[d]) * SCALE_L2E);
  } else {
    int i = d - 128;                        // 0..31
    float ang = (float)row * powf(10000.0f, -(float)i / 32.0f);
    float c = cosf(ang), s = sinf(ang);
    float x1 = bf2f(src[128 + i]), x2 = bf2f(src[160 + i]);
    dst[128 + i] = f2bf((x1 * c - x2 * s) * SCALE_L2E);
    dst[160 + i] = f2bf((x2 * c + x1 * s) * SCALE_L2E);
  }
}

// ---------------- RoPE on k_pe (fp32 in, NOT scaled) ----------------
__global__ __launch_bounds__(256) void k_rope_k(const float* __restrict__ kvlp,
                                                short* __restrict__ kpe) {
  int idx = blockIdx.x * 256 + threadIdx.x;  // SEQ*32
  int row = idx >> 5, i = idx & 31;
  const float* src = kvlp + (size_t)row * KVAW_N + KVLR;
  float ang = (float)row * powf(10000.0f, -(float)i / 32.0f);
  float c = cosf(ang), s = sinf(ang);
  float x1 = src[i], x2 = src[i + 32];
  kpe[(size_t)row * ROPED + i]      = f2bf(x1 * c - x2 * s);
  kpe[(size_t)row * ROPED + i + 32] = f2bf(x2 * c + x1 * s);
}

// ---------------- split-KV causal flash attention, barrier-free ----------------
// grid (NSEG, 16, NH), block 256 = 4 independent waves; wave owns 32 q rows.
// K and V^T MFMA fragments loaded DIRECTLY from global (no LDS staging, no
// __syncthreads; L1 absorbs intra-block redundancy). Wave-private P LDS only.
// K-rope (cols 128..191) comes from kpe via a merged per-row pointer select.
__global__ __launch_bounds__(256) void k_attn4(
    const short* __restrict__ qb,   // [SEQ][NQH] prescaled by SCALE_L2E
    const short* __restrict__ kvb,  // [SEQ][NKVC] (K-nope half valid)
    const short* __restrict__ kpe,  // [SEQ][ROPED]
    const short* __restrict__ vT,   // [NH*128][SEQ]
    short* __restrict__ Opart,      // [NSEG][SEQ][NOV] normalized partials
    float2* __restrict__ mlb)       // [NSEG][SEQ][NH]
{
  __shared__ short Pl[4 * 32 * 72];
  const int tid = threadIdx.x;
  const int lane = tid & 63, w = tid >> 6;
  const int quad = lane >> 4, l16 = lane & 15;
  const int sgi = blockIdx.x;
  const int qt = 15 - (int)blockIdx.y;   // long tiles first
  const int h = blockIdx.z;
  const int q0 = qt * 128;
  const int nch = 2 * qt + 2;
  const int cs = sgi * 8;
  int ce = (nch < cs + 8) ? nch : (cs + 8);
  if (cs >= ce) return;
  const int qw = q0 + w * 32;
  // per-wave: last chunk with any unmasked col: kv0 <= qw+31
  {
    int ce_w = (qw + 32 + 63) >> 6;
    if (ce_w < ce) ce = ce_w;
  }
  short* Plw = Pl + w * (32 * 72);

  short8 qf[2][6];
#pragma unroll
  for (int nt = 0; nt < 2; ++nt)
#pragma unroll
    for (int ks = 0; ks < 6; ++ks)
      qf[nt][ks] = *(const short8*)(qb + (size_t)(qw + nt*16 + l16) * NQH
                                    + h * QHD + ks * 32 + quad * 8);

  floatx4 oacc[8][2] = {};
  float m_i[2] = {-1e30f, -1e30f}, l_i[2] = {0.f, 0.f};

  for (int kc = cs; kc < ce; ++kc) {
    const int kv0 = kc * 64;

    // ----- S^T = K * Q^T, K frags direct from global -----
    floatx4 s[4][2] = {};
#pragma unroll
    for (int mt = 0; mt < 4; ++mt) {
      const short* krow_n = kvb + (size_t)(kv0 + mt*16 + l16) * NKVC + h * 256;
      const short* krow_r = kpe + (size_t)(kv0 + mt*16 + l16) * ROPED;
#pragma unroll
      for (int ks = 0; ks < 6; ++ks) {
        const short* src = (ks < 4) ? (krow_n + ks * 32 + quad * 8)
                                    : (krow_r + (ks - 4) * 32 + quad * 8);
        short8 kf = *(const short8*)src;
        s[mt][0] = __builtin_amdgcn_mfma_f32_16x16x32_bf16(kf, qf[0][ks], s[mt][0], 0, 0, 0);
        s[mt][1] = __builtin_amdgcn_mfma_f32_16x16x32_bf16(kf, qf[1][ks], s[mt][1], 0, 0, 0);
      }
    }

    const bool diag = (kv0 + 64 > qw);
#pragma unroll
    for (int nt = 0; nt < 2; ++nt) {
      const int qg = qw + nt * 16 + l16;
      float mx = -1e30f;
#pragma unroll
      for (int mt = 0; mt < 4; ++mt) {
#pragma unroll
        for (int r = 0; r < 4; ++r) {
          float v = s[mt][nt][r];
          if (diag) {
            int kvg = kv0 + mt * 16 + quad * 4 + r;
            v = (kvg <= qg) ? v : -1e30f;
            s[mt][nt][r] = v;
          }
          mx = fmaxf(mx, v);
        }
      }
      mx = fmaxf(mx, __shfl_xor(mx, 16));
      mx = fmaxf(mx, __shfl_xor(mx, 32));
      float mnew = fmaxf(m_i[nt], mx);
      float alpha = exp2f(m_i[nt] - mnew);
      m_i[nt] = mnew;
      float ssum = 0.f;
#pragma unroll
      for (int mt = 0; mt < 4; ++mt) {
        float p0 = exp2f(s[mt][nt][0] - mnew);
        float p1 = exp2f(s[mt][nt][1] - mnew);
        float p2 = exp2f(s[mt][nt][2] - mnew);
        float p3 = exp2f(s[mt][nt][3] - mnew);
        ssum += (p0 + p1) + (p2 + p3);
        short4v pk; pk.x = f2bf(p0); pk.y = f2bf(p1); pk.z = f2bf(p2); pk.w = f2bf(p3);
        *(short4v*)(Plw + (nt*16 + l16) * 72 + mt * 16 + quad * 4) = pk;
      }
      ssum += __shfl_xor(ssum, 16);
      ssum += __shfl_xor(ssum, 32);
      l_i[nt] = l_i[nt] * alpha + ssum;
#pragma unroll
      for (int dt = 0; dt < 8; ++dt)
#pragma unroll
        for (int r = 0; r < 4; ++r) oacc[dt][nt][r] *= alpha;
    }

    // ----- O^T += V^T * P^T, V frags direct from global -----
#pragma unroll
    for (int kc2 = 0; kc2 < 2; ++kc2) {
      short8 pf[2];
#pragma unroll
      for (int nt = 0; nt < 2; ++nt)
        pf[nt] = *(const short8*)(Plw + (nt*16 + l16) * 72 + kc2 * 32 + quad * 8);
#pragma unroll
      for (int dt = 0; dt < 8; ++dt) {
        short8 vf = *(const short8*)(vT + (size_t)(h * 128 + dt*16 + l16) * SEQ
                                     + kv0 + kc2 * 32 + quad * 8);
#pragma unroll
        for (int nt = 0; nt < 2; ++nt)
          oacc[dt][nt] = __builtin_amdgcn_mfma_f32_16x16x32_bf16(vf, pf[nt], oacc[dt][nt], 0, 0, 0);
      }
    }
  }

  // epilogue: store normalized partial + (m,l)
#pragma unroll
  for (int nt = 0; nt < 2; ++nt) {
    float inv = (l_i[nt] > 0.f) ? 1.f / l_i[nt] : 0.f;
    int q = qw + nt * 16 + l16;
    if (quad == 0)
      mlb[((size_t)sgi * SEQ + q) * NH + h] = make_float2(m_i[nt], l_i[nt]);
#pragma unroll
    for (int dt = 0; dt < 8; ++dt) {
      short4v pk;
      pk.x = f2bf(oacc[dt][nt][0] * inv);
      pk.y = f2bf(oacc[dt][nt][1] * inv);
      pk.z = f2bf(oacc[dt][nt][2] * inv);
      pk.w = f2bf(oacc[dt][nt][3] * inv);
      *(short4v*)(Opart + ((size_t)sgi * SEQ + q) * NOV + h * VH + dt * 16 + quad * 4) = pk;
    }
  }
}

// ---------------- split-KV combiner ----------------
__global__ __launch_bounds__(256) void k_comb(
    const short* __restrict__ Opart, const float2* __restrict__ mlb,
    short* __restrict__ ob)
{
  int q = blockIdx.x;
  int hd0 = threadIdx.x * 8;
  int h = hd0 >> 7;
  int nact = (q >> 9) + 1;
  float2 mlv[NSEG];
  float M = -1e30f;
  for (int s = 0; s < nact; ++s) {
    mlv[s] = mlb[((size_t)s * SEQ + q) * NH + h];
    M = fmaxf(M, mlv[s].x);
  }
  float wgt[NSEG]; float L = 0.f;
  for (int s = 0; s < nact; ++s) {
    wgt[s] = mlv[s].y * exp2f(mlv[s].x - M);
    L += wgt[s];
  }
  float invL = 1.0f / L;
  float acc[8] = {};
  for (int s = 0; s < nact; ++s) {
    short8 o = *(const short8*)(Opart + ((size_t)s * SEQ + q) * NOV + hd0);
    float ws = wgt[s] * invL;
#pragma unroll
    for (int j = 0; j < 8; ++j) acc[j] += ws * bf2f(o[j]);
  }
  short8 r;
#pragma unroll
  for (int j = 0; j < 8; ++j) r[j] = f2bf(acc[j]);
  *(short8*)(ob + (size_t)q * NOV + hd0) = r;
}

// ---------------- launch ----------------
extern "C" void kernel_launch(void* const* d_in, const int* in_sizes, int n_in,
                              void* d_out, int out_size, void* d_ws, size_t ws_size,
                              hipStream_t stream) {
  const float* hs      = (const float*)d_in[0];
  const float* q_a_w   = (const float*)d_in[1];
  const float* q_a_ln  = (const float*)d_in[2];
  const float* q_b_w   = (const float*)d_in[3];
  const float* kv_a_w  = (const float*)d_in[4];
  const float* kv_a_ln = (const float*)d_in[5];
  const float* kv_b_w  = (const float*)d_in[6];
  const float* o_w     = (const float*)d_in[7];
  float* out = (float*)d_out;

  char* ws = (char*)d_ws;
  size_t off = 0;
  auto alloc = [&](size_t bytes) {
    void* p = ws + off;
    off += (bytes + 255) & ~(size_t)255;
    return p;
  };
  const size_t MB = 1u << 20;
  short* hs_b   = (short*)alloc((size_t)SEQ * H * 2);
  short* qaw_b  = (short*)alloc((size_t)QLR * H * 2);
  short* qbw_b  = (short*)alloc((size_t)NQH * QLR * 2);
  short* kvaw_b = (short*)alloc((size_t)KVAW_N * H * 2);
  short* kvbw_b = (short*)alloc((size_t)NKVC * KVLR * 2);
  short* ow_b   = (short*)alloc((size_t)H * NOV * 2);
  short* qbf    = (short*)alloc((size_t)SEQ * NQH * 2);
  short* kpeb   = (short*)alloc((size_t)SEQ * ROPED * 2);
  short* kvbuf  = (short*)alloc((size_t)SEQ * NKVC * 2);
  short* vT     = (short*)alloc((size_t)NH * VH * SEQ * 2);
  short* attnb  = (short*)alloc((size_t)SEQ * NOV * 2);
  // overlay region (36 MB): phase-disjoint temporaries
  char* R = (char*)alloc(36 * MB);
  float* qlat  = (float*)R;                 // [SEQ][QLR] fp32   (phase 1)
  short* qlatn = (short*)(R + 13 * MB);     // [SEQ][QLR] bf16   (phase 1-2)
  short* qtmp  = (short*)R;                 // [SEQ][NQH] bf16   (phase 2)
  float* kvlp  = (float*)R;                 // [SEQ][KVAW_N] fp32 (phase 3)
  short* kvln  = (short*)(R + 20 * MB);     // [SEQ][KVLR] bf16  (phase 3-4)
  short* Opart = (short*)R;                 // [NSEG][SEQ][NOV] bf16 (attn)
  float2* mlb  = (float2*)(R + 34 * MB);    // [NSEG][SEQ][NH]   (attn)

  auto cvt = [&](const float* x, short* y, size_t n) {
    int n4 = (int)(n / 4);
    k_cvt_bf16<<<dim3((n4 + 255) / 256), 256, 0, stream>>>(x, y, n4);
  };
  cvt(hs,     hs_b,   (size_t)SEQ * H);
  cvt(q_a_w,  qaw_b,  (size_t)QLR * H);
  cvt(q_b_w,  qbw_b,  (size_t)NQH * QLR);
  cvt(kv_a_w, kvaw_b, (size_t)KVAW_N * H);
  cvt(kv_b_w, kvbw_b, (size_t)NKVC * KVLR);
  cvt(o_w,    ow_b,   (size_t)H * NOV);

  // q_lat = hs @ q_a_w^T (fp32)
  k_gemm_nt<0><<<dim3(SEQ/128, QLR/128), 256, 0, stream>>>(hs_b, qaw_b, qlat, nullptr, SEQ, QLR, H);
  k_rmsnorm<<<SEQ, 256, 0, stream>>>(qlat, QLR, q_a_ln, qlatn, QLR);
  // q = q_lat_n @ q_b_w^T (bf16)
  k_gemm_nt<1><<<dim3(SEQ/128, NQH/128), 256, 0, stream>>>(qlatn, qbw_b, qtmp, nullptr, SEQ, NQH, QLR);
  k_rope_q<<<dim3(10, SEQ), 256, 0, stream>>>(qtmp, qbf);
  // kv_lat_pe = hs @ kv_a_w^T (fp32)
  k_gemm_nt<0><<<dim3(SEQ/128, (KVAW_N+127)/128), 256, 0, stream>>>(hs_b, kvaw_b, kvlp, nullptr, SEQ, KVAW_N, H);
  k_rmsnorm<<<SEQ, 256, 0, stream>>>(kvlp, KVAW_N, kv_a_ln, kvln, KVLR);
  k_rope_k<<<(SEQ*32)/256, 256, 0, stream>>>(kvlp, kpeb);
  // kv = kv_lat_n @ kv_b_w^T : K half -> kvbuf, V half -> vT (transposed)
  k_gemm_nt<2><<<dim3(SEQ/128, NKVC/128), 256, 0, stream>>>(kvln, kvbw_b, kvbuf, vT, SEQ, NKVC, KVLR);
  // barrier-free split-KV attention + combine
  k_attn4<<<dim3(NSEG, 16, NH), 256, 0, stream>>>(qbf, kvbuf, kpeb, vT, Opart, mlb);
  k_comb<<<SEQ, 256, 0, stream>>>(Opart, mlb, attnb);
  // out = attn @ o_w^T (fp32)
  k_gemm_nt<0><<<dim3(SEQ/128, H/128), 256, 0, stream>>>(attnb, ow_b, out, nullptr, SEQ, H, NOV);
}

// Round 5
// 513.470 us; speedup vs baseline: 1.2888x; 1.2661x over previous
//
#include <hip/hip_runtime.h>
#include <cstdint>

#define H 2048
#define NH 16
#define QLR 1536
#define KVLR 512
#define NOPE 128
#define ROPED 64
#define VH 128
#define QHD 192
#define SEQ 2048
#define NQH (NH*QHD)        // 3072
#define NKVC (NH*(NOPE+VH)) // 4096
#define NOV (NH*VH)         // 2048
#define KVAW_N (KVLR+ROPED) // 576
#define SCALE_L2E 0.10411755f   // 192^-0.5 * log2(e)
#define NSEG 4

typedef __attribute__((ext_vector_type(8))) short short8;
typedef __attribute__((ext_vector_type(4))) short short4v;
typedef __attribute__((ext_vector_type(4))) float floatx4;

__device__ __forceinline__ short f2bf(float x) {
  unsigned u = __builtin_bit_cast(unsigned, x);
  unsigned r = (u + 0x7FFFu + ((u >> 16) & 1u)) >> 16;
  return (short)(unsigned short)r;
}
__device__ __forceinline__ float bf2f(short s) {
  unsigned u = ((unsigned)(unsigned short)s) << 16;
  return __builtin_bit_cast(float, u);
}
__device__ __forceinline__ void g2l16(const void* g, void* l) {
  __builtin_amdgcn_global_load_lds(
      (const __attribute__((address_space(1))) void*)(uintptr_t)(g),
      (__attribute__((address_space(3))) void*)(uintptr_t)(l),
      16, 0, 0);
}

// ---------------- fused fp32 -> bf16 convert (all 6 tensors) ----------------
struct CvtArgs {
  const float* src[6];
  short* dst[6];
  int cum[7];   // cumulative float4 counts
};
__global__ __launch_bounds__(256) void k_cvt_all(CvtArgs a, int total4) {
  int stride = gridDim.x * 256;
  for (int i = blockIdx.x * 256 + threadIdx.x; i < total4; i += stride) {
    int j = 0;
#pragma unroll
    for (int t = 1; t < 6; ++t) j += (i >= a.cum[t]);
    int loc = i - a.cum[j];
    float4 v = ((const float4*)a.src[j])[loc];
    short4v o;
    o.x = f2bf(v.x); o.y = f2bf(v.y); o.z = f2bf(v.z); o.w = f2bf(v.w);
    ((short4v*)a.dst[j])[loc] = o;
  }
}

// ---------------- pipelined NT GEMM: C[M,N] = A[M,K]*B[N,K]^T ----------------
// 3-deep LDS ring; global_load_lds issued 2 tiles ahead; raw s_barrier +
// fine-grained vmcnt so loads stay in flight across barriers (no vmcnt(0)
// drain until the last tile).  MODE 0: fp32 out. 1: bf16. 2: kv-special.
template<int MODE>
__global__ __launch_bounds__(256) void k_gemm_nt(
    const short* __restrict__ A, const short* __restrict__ B,
    void* __restrict__ C, short* __restrict__ C2, int M, int N, int K)
{
  __shared__ short As[3][4096];
  __shared__ short Bs[3][4096];
  const int tid = threadIdx.x;
  const int lane = tid & 63;
  const int w = tid >> 6;
  const int wm = w & 1, wn = w >> 1;
  const int quad = lane >> 4, l16 = lane & 15;
  const int m0 = blockIdx.x * 128, n0 = blockIdx.y * 128;
  const int T = K >> 5;

  floatx4 acc[4][4] = {};

  auto issue = [&](int t, int buf) {
#pragma unroll
    for (int i = 0; i < 2; ++i) {
      int c = i*256 + tid;
      int row = c & 127, koct = c >> 7;
      g2l16(A + (size_t)(m0 + row)*K + t*32 + koct*8, As[buf] + (i*256 + w*64)*8);
      int nrow = n0 + row; nrow = (nrow < N) ? nrow : (N-1);
      g2l16(B + (size_t)nrow*K + t*32 + koct*8,      Bs[buf] + (i*256 + w*64)*8);
    }
  };

  issue(0, 0);
  issue(1, 1);
  int buf = 0;
  for (int t = 0; t < T; ++t) {
    if (t + 2 < T) {
      int nb = buf - 1; if (nb < 0) nb = 2;      // (t+2)%3
      issue(t + 2, nb);
      asm volatile("s_waitcnt vmcnt(8)" ::: "memory");
    } else if (t + 1 < T) {
      asm volatile("s_waitcnt vmcnt(4)" ::: "memory");
    } else {
      asm volatile("s_waitcnt vmcnt(0)" ::: "memory");
    }
    asm volatile("s_barrier" ::: "memory");      // tile t staged for all waves
    short8 af[4], bfr[4];
#pragma unroll
    for (int mi = 0; mi < 4; ++mi)
      af[mi] = *(const short8*)(As[buf] + (quad*128 + wm*64 + mi*16 + l16)*8);
#pragma unroll
    for (int ni = 0; ni < 4; ++ni)
      bfr[ni] = *(const short8*)(Bs[buf] + (quad*128 + wn*64 + ni*16 + l16)*8);
#pragma unroll
    for (int mi = 0; mi < 4; ++mi)
#pragma unroll
      for (int ni = 0; ni < 4; ++ni)
        acc[mi][ni] = __builtin_amdgcn_mfma_f32_16x16x32_bf16(af[mi], bfr[ni], acc[mi][ni], 0, 0, 0);
    asm volatile("s_barrier" ::: "memory");      // all waves done reading buf
    buf = buf + 1; if (buf > 2) buf = 0;
  }

  if (MODE == 2 && (n0 & 128)) {
#pragma unroll
    for (int mi = 0; mi < 4; ++mi) {
#pragma unroll
      for (int ni = 0; ni < 4; ++ni) {
        int col = n0 + wn*64 + ni*16 + l16;
        int h = col >> 8, dv = (col & 255) - 128;
        int row = m0 + wm*64 + mi*16 + quad*4;
        short4v pk;
        pk.x = f2bf(acc[mi][ni][0]); pk.y = f2bf(acc[mi][ni][1]);
        pk.z = f2bf(acc[mi][ni][2]); pk.w = f2bf(acc[mi][ni][3]);
        *(short4v*)(C2 + (size_t)(h*128 + dv)*SEQ + row) = pk;
      }
    }
    return;
  }

#pragma unroll
  for (int mi = 0; mi < 4; ++mi) {
#pragma unroll
    for (int ni = 0; ni < 4; ++ni) {
      int col = n0 + wn*64 + ni*16 + l16;
      if (col < N) {
#pragma unroll
        for (int r = 0; r < 4; ++r) {
          int row = m0 + wm*64 + mi*16 + quad*4 + r;
          if (MODE == 0)
            ((float*)C)[(size_t)row*N + col] = acc[mi][ni][r];
          else
            ((short*)C)[(size_t)row*N + col] = f2bf(acc[mi][ni][r]);
        }
      }
    }
  }
}

// ---------------- RMS norm (row-wise, fp32 -> bf16) ----------------
__global__ __launch_bounds__(256) void k_rmsnorm(
    const float* __restrict__ x, int xstride,
    const float* __restrict__ w, short* __restrict__ y, int L)
{
  int row = blockIdx.x;
  const float* xr = x + (size_t)row * xstride;
  float s = 0.f;
  for (int i = threadIdx.x; i < L; i += 256) { float v = xr[i]; s += v*v; }
#pragma unroll
  for (int off = 1; off < 64; off <<= 1) s += __shfl_xor(s, off);
  __shared__ float red[4];
  if ((threadIdx.x & 63) == 0) red[threadIdx.x >> 6] = s;
  __syncthreads();
  float tot = red[0] + red[1] + red[2] + red[3];
  float inv = rsqrtf(tot / (float)L + 1e-6f);
  for (int i = threadIdx.x; i < L; i += 256)
    y[(size_t)row * L + i] = f2bf(xr[i] * inv * w[i]);
}

// ---------------- RoPE+prescale on q (bf16 in -> bf16 out) ----------------
__global__ __launch_bounds__(256) void k_rope_q(const short* __restrict__ q,
                                                short* __restrict__ qb) {
  int row = blockIdx.y;
  int t2 = blockIdx.x * 256 + threadIdx.x;  // 0..2559
  int h = t2 / 160, d = t2 - h * 160;
  const short* src = q + (size_t)row * NQH + h * QHD;
  short* dst = qb + (size_t)row * NQH + h * QHD;
  if (d < 128) {
    dst[d] = f2bf(bf2f(src[d]) * SCALE_L2E);
  } else {
    int i = d - 128;                        // 0..31
    float ang = (float)row * powf(10000.0f, -(float)i / 32.0f);
    float c = cosf(ang), s = sinf(ang);
    float x1 = bf2f(src[128 + i]), x2 = bf2f(src[160 + i]);
    dst[128 + i] = f2bf((x1 * c - x2 * s) * SCALE_L2E);
    dst[160 + i] = f2bf((x2 * c + x1 * s) * SCALE_L2E);
  }
}

// ---------------- RoPE on k_pe (fp32 in, NOT scaled) ----------------
__global__ __launch_bounds__(256) void k_rope_k(const float* __restrict__ kvlp,
                                                short* __restrict__ kpe) {
  int idx = blockIdx.x * 256 + threadIdx.x;  // SEQ*32
  int row = idx >> 5, i = idx & 31;
  const float* src = kvlp + (size_t)row * KVAW_N + KVLR;
  float ang = (float)row * powf(10000.0f, -(float)i / 32.0f);
  float c = cosf(ang), s = sinf(ang);
  float x1 = src[i], x2 = src[i + 32];
  kpe[(size_t)row * ROPED + i]      = f2bf(x1 * c - x2 * s);
  kpe[(size_t)row * ROPED + i + 32] = f2bf(x2 * c + x1 * s);
}

// ---------------- balanced wave-scheduled causal flash attention ----------------
// 2560 wave-segments, exactly enumerated (no dead waves). Each wave owns 32 q
// rows and <=8 kv chunks of 64. K/V frags direct from global (no barriers).
// Per head: qw 0..15 -> 1 seg, 16..31 -> 2, 32..47 -> 3, 48..63 -> 4  (160/head).
__global__ __launch_bounds__(256) void k_attn5(
    const short* __restrict__ qb,   // [SEQ][NQH] prescaled by SCALE_L2E
    const short* __restrict__ kvb,  // [SEQ][NKVC] (K-nope half valid)
    const short* __restrict__ kpe,  // [SEQ][ROPED]
    const short* __restrict__ vT,   // [NH*128][SEQ]
    short* __restrict__ Opart,      // [NSEG][SEQ][NOV] normalized partials
    float2* __restrict__ mlb)       // [NSEG][SEQ][NH]
{
  __shared__ short Pl[4 * 32 * 72];
  const int tid = threadIdx.x;
  const int lane = tid & 63, w = tid >> 6;
  const int quad = lane >> 4, l16 = lane & 15;
  const int sid = blockIdx.x * 4 + w;       // 0..2559
  const int h = sid / 160;
  const int r = sid - h * 160;
  int qw, seg;
  if (r < 16)      { qw = r;                          seg = 0; }
  else if (r < 48) { int x = r - 16; qw = 16 + (x >> 1); seg = x & 1; }
  else if (r < 96) { int x = r - 48; int d3 = x / 3; qw = 32 + d3; seg = x - 3 * d3; }
  else             { int x = r - 96; qw = 48 + (x >> 2); seg = x & 3; }
  const int qws = qw * 32;                  // first q row of this wave
  const int ce = (qw >> 1) + 1;             // total chunks for this q range
  const int cs = seg * 8;
  const int cend = (ce < cs + 8) ? ce : (cs + 8);
  short* Plw = Pl + w * (32 * 72);

  short8 qf[2][6];
#pragma unroll
  for (int nt = 0; nt < 2; ++nt)
#pragma unroll
    for (int ks = 0; ks < 6; ++ks)
      qf[nt][ks] = *(const short8*)(qb + (size_t)(qws + nt*16 + l16) * NQH
                                    + h * QHD + ks * 32 + quad * 8);

  floatx4 oacc[8][2] = {};
  float m_i[2] = {-1e30f, -1e30f}, l_i[2] = {0.f, 0.f};

  for (int kc = cs; kc < cend; ++kc) {
    const int kv0 = kc * 64;

    // ----- S^T = K * Q^T, K frags direct from global -----
    floatx4 s[4][2] = {};
#pragma unroll
    for (int mt = 0; mt < 4; ++mt) {
      const short* krow_n = kvb + (size_t)(kv0 + mt*16 + l16) * NKVC + h * 256;
      const short* krow_r = kpe + (size_t)(kv0 + mt*16 + l16) * ROPED;
#pragma unroll
      for (int ks = 0; ks < 6; ++ks) {
        const short* src = (ks < 4) ? (krow_n + ks * 32 + quad * 8)
                                    : (krow_r + (ks - 4) * 32 + quad * 8);
        short8 kf = *(const short8*)src;
        s[mt][0] = __builtin_amdgcn_mfma_f32_16x16x32_bf16(kf, qf[0][ks], s[mt][0], 0, 0, 0);
        s[mt][1] = __builtin_amdgcn_mfma_f32_16x16x32_bf16(kf, qf[1][ks], s[mt][1], 0, 0, 0);
      }
    }

    const bool diag = (kv0 + 64 > qws);
#pragma unroll
    for (int nt = 0; nt < 2; ++nt) {
      const int qg = qws + nt * 16 + l16;
      float mx = -1e30f;
#pragma unroll
      for (int mt = 0; mt < 4; ++mt) {
#pragma unroll
        for (int rr = 0; rr < 4; ++rr) {
          float v = s[mt][nt][rr];
          if (diag) {
            int kvg = kv0 + mt * 16 + quad * 4 + rr;
            v = (kvg <= qg) ? v : -1e30f;
            s[mt][nt][rr] = v;
          }
          mx = fmaxf(mx, v);
        }
      }
      mx = fmaxf(mx, __shfl_xor(mx, 16));
      mx = fmaxf(mx, __shfl_xor(mx, 32));
      float mnew = fmaxf(m_i[nt], mx);
      float alpha = exp2f(m_i[nt] - mnew);
      m_i[nt] = mnew;
      float ssum = 0.f;
#pragma unroll
      for (int mt = 0; mt < 4; ++mt) {
        float p0 = exp2f(s[mt][nt][0] - mnew);
        float p1 = exp2f(s[mt][nt][1] - mnew);
        float p2 = exp2f(s[mt][nt][2] - mnew);
        float p3 = exp2f(s[mt][nt][3] - mnew);
        ssum += (p0 + p1) + (p2 + p3);
        short4v pk; pk.x = f2bf(p0); pk.y = f2bf(p1); pk.z = f2bf(p2); pk.w = f2bf(p3);
        *(short4v*)(Plw + (nt*16 + l16) * 72 + mt * 16 + quad * 4) = pk;
      }
      ssum += __shfl_xor(ssum, 16);
      ssum += __shfl_xor(ssum, 32);
      l_i[nt] = l_i[nt] * alpha + ssum;
#pragma unroll
      for (int dt = 0; dt < 8; ++dt)
#pragma unroll
        for (int rr = 0; rr < 4; ++rr) oacc[dt][nt][rr] *= alpha;
    }

    // ----- O^T += V^T * P^T, V frags direct from global -----
#pragma unroll
    for (int kc2 = 0; kc2 < 2; ++kc2) {
      short8 pf[2];
#pragma unroll
      for (int nt = 0; nt < 2; ++nt)
        pf[nt] = *(const short8*)(Plw + (nt*16 + l16) * 72 + kc2 * 32 + quad * 8);
#pragma unroll
      for (int dt = 0; dt < 8; ++dt) {
        short8 vf = *(const short8*)(vT + (size_t)(h * 128 + dt*16 + l16) * SEQ
                                     + kv0 + kc2 * 32 + quad * 8);
#pragma unroll
        for (int nt = 0; nt < 2; ++nt)
          oacc[dt][nt] = __builtin_amdgcn_mfma_f32_16x16x32_bf16(vf, pf[nt], oacc[dt][nt], 0, 0, 0);
      }
    }
  }

  // epilogue: store normalized partial + (m,l)
#pragma unroll
  for (int nt = 0; nt < 2; ++nt) {
    float inv = (l_i[nt] > 0.f) ? 1.f / l_i[nt] : 0.f;
    int q = qws + nt * 16 + l16;
    if (quad == 0)
      mlb[((size_t)seg * SEQ + q) * NH + h] = make_float2(m_i[nt], l_i[nt]);
#pragma unroll
    for (int dt = 0; dt < 8; ++dt) {
      short4v pk;
      pk.x = f2bf(oacc[dt][nt][0] * inv);
      pk.y = f2bf(oacc[dt][nt][1] * inv);
      pk.z = f2bf(oacc[dt][nt][2] * inv);
      pk.w = f2bf(oacc[dt][nt][3] * inv);
      *(short4v*)(Opart + ((size_t)seg * SEQ + q) * NOV + h * VH + dt * 16 + quad * 4) = pk;
    }
  }
}

// ---------------- split-KV combiner ----------------
__global__ __launch_bounds__(256) void k_comb(
    const short* __restrict__ Opart, const float2* __restrict__ mlb,
    short* __restrict__ ob)
{
  int q = blockIdx.x;
  int hd0 = threadIdx.x * 8;
  int h = hd0 >> 7;
  int nact = (q >> 9) + 1;   // = ceil(((q/64)+1)/8) for q<2048
  float2 mlv[NSEG];
  float M = -1e30f;
  for (int s = 0; s < nact; ++s) {
    mlv[s] = mlb[((size_t)s * SEQ + q) * NH + h];
    M = fmaxf(M, mlv[s].x);
  }
  float wgt[NSEG]; float L = 0.f;
  for (int s = 0; s < nact; ++s) {
    wgt[s] = mlv[s].y * exp2f(mlv[s].x - M);
    L += wgt[s];
  }
  float invL = 1.0f / L;
  float acc[8] = {};
  for (int s = 0; s < nact; ++s) {
    short8 o = *(const short8*)(Opart + ((size_t)s * SEQ + q) * NOV + hd0);
    float ws = wgt[s] * invL;
#pragma unroll
    for (int j = 0; j < 8; ++j) acc[j] += ws * bf2f(o[j]);
  }
  short8 rr;
#pragma unroll
  for (int j = 0; j < 8; ++j) rr[j] = f2bf(acc[j]);
  *(short8*)(ob + (size_t)q * NOV + hd0) = rr;
}

// ---------------- launch ----------------
extern "C" void kernel_launch(void* const* d_in, const int* in_sizes, int n_in,
                              void* d_out, int out_size, void* d_ws, size_t ws_size,
                              hipStream_t stream) {
  const float* hs      = (const float*)d_in[0];
  const float* q_a_w   = (const float*)d_in[1];
  const float* q_a_ln  = (const float*)d_in[2];
  const float* q_b_w   = (const float*)d_in[3];
  const float* kv_a_w  = (const float*)d_in[4];
  const float* kv_a_ln = (const float*)d_in[5];
  const float* kv_b_w  = (const float*)d_in[6];
  const float* o_w     = (const float*)d_in[7];
  float* out = (float*)d_out;

  char* ws = (char*)d_ws;
  size_t off = 0;
  auto alloc = [&](size_t bytes) {
    void* p = ws + off;
    off += (bytes + 255) & ~(size_t)255;
    return p;
  };
  const size_t MB = 1u << 20;
  short* hs_b   = (short*)alloc((size_t)SEQ * H * 2);
  short* qaw_b  = (short*)alloc((size_t)QLR * H * 2);
  short* qbw_b  = (short*)alloc((size_t)NQH * QLR * 2);
  short* kvaw_b = (short*)alloc((size_t)KVAW_N * H * 2);
  short* kvbw_b = (short*)alloc((size_t)NKVC * KVLR * 2);
  short* ow_b   = (short*)alloc((size_t)H * NOV * 2);
  short* qbf    = (short*)alloc((size_t)SEQ * NQH * 2);
  short* kpeb   = (short*)alloc((size_t)SEQ * ROPED * 2);
  short* kvbuf  = (short*)alloc((size_t)SEQ * NKVC * 2);
  short* vT     = (short*)alloc((size_t)NH * VH * SEQ * 2);
  short* attnb  = (short*)alloc((size_t)SEQ * NOV * 2);
  // overlay region (36 MB): phase-disjoint temporaries
  char* R = (char*)alloc(36 * MB);
  float* qlat  = (float*)R;                 // [SEQ][QLR] fp32   (phase 1)
  short* qlatn = (short*)(R + 13 * MB);     // [SEQ][QLR] bf16   (phase 1-2)
  short* qtmp  = (short*)R;                 // [SEQ][NQH] bf16   (phase 2)
  float* kvlp  = (float*)R;                 // [SEQ][KVAW_N] fp32 (phase 3)
  short* kvln  = (short*)(R + 20 * MB);     // [SEQ][KVLR] bf16  (phase 3-4)
  short* Opart = (short*)R;                 // [NSEG][SEQ][NOV] bf16 (attn)
  float2* mlb  = (float2*)(R + 34 * MB);    // [NSEG][SEQ][NH]   (attn)

  // single fused convert
  CvtArgs ca;
  ca.src[0] = hs;     ca.dst[0] = hs_b;
  ca.src[1] = q_a_w;  ca.dst[1] = qaw_b;
  ca.src[2] = q_b_w;  ca.dst[2] = qbw_b;
  ca.src[3] = kv_a_w; ca.dst[3] = kvaw_b;
  ca.src[4] = kv_b_w; ca.dst[4] = kvbw_b;
  ca.src[5] = o_w;    ca.dst[5] = ow_b;
  int sizes4[6] = { SEQ*H/4, QLR*H/4, NQH*QLR/4, KVAW_N*H/4, NKVC*KVLR/4, H*NOV/4 };
  ca.cum[0] = 0;
  for (int i = 0; i < 6; ++i) ca.cum[i+1] = ca.cum[i] + sizes4[i];
  int total4 = ca.cum[6];
  k_cvt_all<<<2048, 256, 0, stream>>>(ca, total4);

  // q_lat = hs @ q_a_w^T (fp32)
  k_gemm_nt<0><<<dim3(SEQ/128, QLR/128), 256, 0, stream>>>(hs_b, qaw_b, qlat, nullptr, SEQ, QLR, H);
  k_rmsnorm<<<SEQ, 256, 0, stream>>>(qlat, QLR, q_a_ln, qlatn, QLR);
  // q = q_lat_n @ q_b_w^T (bf16)
  k_gemm_nt<1><<<dim3(SEQ/128, NQH/128), 256, 0, stream>>>(qlatn, qbw_b, qtmp, nullptr, SEQ, NQH, QLR);
  k_rope_q<<<dim3(10, SEQ), 256, 0, stream>>>(qtmp, qbf);
  // kv_lat_pe = hs @ kv_a_w^T (fp32)
  k_gemm_nt<0><<<dim3(SEQ/128, (KVAW_N+127)/128), 256, 0, stream>>>(hs_b, kvaw_b, kvlp, nullptr, SEQ, KVAW_N, H);
  k_rmsnorm<<<SEQ, 256, 0, stream>>>(kvlp, KVAW_N, kv_a_ln, kvln, KVLR);
  k_rope_k<<<(SEQ*32)/256, 256, 0, stream>>>(kvlp, kpeb);
  // kv = kv_lat_n @ kv_b_w^T : K half -> kvbuf, V half -> vT (transposed)
  k_gemm_nt<2><<<dim3(SEQ/128, NKVC/128), 256, 0, stream>>>(kvln, kvbw_b, kvbuf, vT, SEQ, NKVC, KVLR);
  // balanced wave-scheduled attention + combine
  k_attn5<<<dim3(640), 256, 0, stream>>>(qbf, kvbuf, kpeb, vT, Opart, mlb);
  k_comb<<<SEQ, 256, 0, stream>>>(Opart, mlb, attnb);
  // out = attn @ o_w^T (fp32)
  k_gemm_nt<0><<<dim3(SEQ/128, H/128), 256, 0, stream>>>(attnb, ow_b, out, nullptr, SEQ, H, NOV);
}

// Round 6
// 505.163 us; speedup vs baseline: 1.3100x; 1.0164x over previous
//
#include <hip/hip_runtime.h>
#include <cstdint>

#define H 2048
#define NH 16
#define QLR 1536
#define KVLR 512
#define NOPE 128
#define ROPED 64
#define VH 128
#define QHD 192
#define SEQ 2048
#define NQH (NH*QHD)        // 3072
#define NKVC (NH*(NOPE+VH)) // 4096
#define NOV (NH*VH)         // 2048
#define KVAW_N (KVLR+ROPED) // 576
#define SCALE_L2E 0.10411755f   // 192^-0.5 * log2(e)
#define NSEG 4

typedef __attribute__((ext_vector_type(8))) short short8;
typedef __attribute__((ext_vector_type(4))) short short4v;
typedef __attribute__((ext_vector_type(4))) float floatx4;

__device__ __forceinline__ short f2bf(float x) {
  unsigned u = __builtin_bit_cast(unsigned, x);
  unsigned r = (u + 0x7FFFu + ((u >> 16) & 1u)) >> 16;
  return (short)(unsigned short)r;
}
__device__ __forceinline__ float bf2f(short s) {
  unsigned u = ((unsigned)(unsigned short)s) << 16;
  return __builtin_bit_cast(float, u);
}
__device__ __forceinline__ void g2l16(const void* g, void* l) {
  __builtin_amdgcn_global_load_lds(
      (const __attribute__((address_space(1))) void*)(uintptr_t)(g),
      (__attribute__((address_space(3))) void*)(uintptr_t)(l),
      16, 0, 0);
}

// ---------------- fused fp32 -> bf16 convert ----------------
struct CvtArgs {
  const float* src[6];
  short* dst[6];
  int cum[7];
};
__global__ __launch_bounds__(256) void k_cvt_all(CvtArgs a, int total4) {
  int stride = gridDim.x * 256;
  for (int i = blockIdx.x * 256 + threadIdx.x; i < total4; i += stride) {
    int j = 0;
#pragma unroll
    for (int t = 1; t < 6; ++t) j += (i >= a.cum[t]);
    int loc = i - a.cum[j];
    float4 v = ((const float4*)a.src[j])[loc];
    short4v o;
    o.x = f2bf(v.x); o.y = f2bf(v.y); o.z = f2bf(v.z); o.w = f2bf(v.w);
    ((short4v*)a.dst[j])[loc] = o;
  }
}

// ---------------- BN=64 pipelined NT GEMM (128x64 tile, 3-ring) ----------------
// EPI 0: fp32 C[row*N+col].
// EPI 1: col<QLR -> qlat (stride QLR); else -> kvlp (stride KVAW_N, col-QLR).
template<int EPI>
__global__ __launch_bounds__(256) void k_gemm64(
    const short* __restrict__ A, const short* __restrict__ B,
    float* __restrict__ C, float* __restrict__ C2, int N, int K)
{
  __shared__ short As[3][4096];   // 128 x 32
  __shared__ short Bs[3][2048];   // 64 x 32
  const int tid = threadIdx.x;
  const int lane = tid & 63;
  const int w = tid >> 6;
  const int wm = w & 1, wn = w >> 1;
  const int quad = lane >> 4, l16 = lane & 15;
  const int m0 = blockIdx.x * 128, n0 = blockIdx.y * 64;
  const int T = K >> 5;

  floatx4 acc[4][2] = {};

  auto issue = [&](int t, int buf) {
#pragma unroll
    for (int i = 0; i < 2; ++i) {
      int c = i*256 + tid;
      int row = c & 127, koct = c >> 7;
      g2l16(A + (size_t)(m0 + row)*K + t*32 + koct*8, As[buf] + (koct*128 + row)*8);
    }
    { int c = tid; int row = c & 63, koct = c >> 6;
      g2l16(B + (size_t)(n0 + row)*K + t*32 + koct*8, Bs[buf] + (koct*64 + row)*8); }
  };

  issue(0, 0);
  issue(1, 1);
  int buf = 0;
  for (int t = 0; t < T; ++t) {
    if (t + 2 < T) {
      int nb = buf - 1; if (nb < 0) nb = 2;
      issue(t + 2, nb);
      asm volatile("s_waitcnt vmcnt(6)" ::: "memory");
    } else if (t + 1 < T) {
      asm volatile("s_waitcnt vmcnt(3)" ::: "memory");
    } else {
      asm volatile("s_waitcnt vmcnt(0)" ::: "memory");
    }
    asm volatile("s_barrier" ::: "memory");
    short8 af[4], bfr[2];
#pragma unroll
    for (int mi = 0; mi < 4; ++mi)
      af[mi] = *(const short8*)(As[buf] + (quad*128 + wm*64 + mi*16 + l16)*8);
#pragma unroll
    for (int ni = 0; ni < 2; ++ni)
      bfr[ni] = *(const short8*)(Bs[buf] + (quad*64 + wn*32 + ni*16 + l16)*8);
#pragma unroll
    for (int mi = 0; mi < 4; ++mi)
#pragma unroll
      for (int ni = 0; ni < 2; ++ni)
        acc[mi][ni] = __builtin_amdgcn_mfma_f32_16x16x32_bf16(af[mi], bfr[ni], acc[mi][ni], 0, 0, 0);
    asm volatile("s_barrier" ::: "memory");
    buf = buf + 1; if (buf > 2) buf = 0;
  }

#pragma unroll
  for (int mi = 0; mi < 4; ++mi) {
#pragma unroll
    for (int ni = 0; ni < 2; ++ni) {
      int col = n0 + wn*32 + ni*16 + l16;
#pragma unroll
      for (int r = 0; r < 4; ++r) {
        int row = m0 + wm*64 + mi*16 + quad*4 + r;
        if (EPI == 0) {
          C[(size_t)row*N + col] = acc[mi][ni][r];
        } else {
          if (col < QLR) C[(size_t)row*QLR + col] = acc[mi][ni][r];
          else           C2[(size_t)row*KVAW_N + (col - QLR)] = acc[mi][ni][r];
        }
      }
    }
  }
}

// ---------------- merged q_b + kv_b GEMM (BN=128, 3-ring) ----------------
__global__ __launch_bounds__(256) void k_gemm2(
    const short* __restrict__ qlatn, const short* __restrict__ qbw,
    const short* __restrict__ kvln,  const short* __restrict__ kvbw,
    short* __restrict__ qhm, short* __restrict__ knope, short* __restrict__ vTd)
{
  __shared__ short As[3][4096];
  __shared__ short Bs[3][4096];
  const int tid = threadIdx.x;
  const int lane = tid & 63;
  const int w = tid >> 6;
  const int wm = w & 1, wn = w >> 1;
  const int quad = lane >> 4, l16 = lane & 15;
  int bid = blockIdx.x;
  const short *A, *B; int K, m0, n0; bool isq;
  if (bid < 384) { isq = true;  A = qlatn; B = qbw;  K = QLR;
    m0 = (bid & 15) * 128; n0 = (bid >> 4) * 128; }
  else { int b2 = bid - 384; isq = false; A = kvln; B = kvbw; K = KVLR;
    m0 = (b2 & 15) * 128; n0 = (b2 >> 4) * 128; }
  const int T = K >> 5;

  floatx4 acc[4][4] = {};

  auto issue = [&](int t, int buf) {
#pragma unroll
    for (int i = 0; i < 2; ++i) {
      int c = i*256 + tid;
      int row = c & 127, koct = c >> 7;
      g2l16(A + (size_t)(m0 + row)*K + t*32 + koct*8, As[buf] + (koct*128 + row)*8);
      g2l16(B + (size_t)(n0 + row)*K + t*32 + koct*8, Bs[buf] + (koct*128 + row)*8);
    }
  };

  issue(0, 0);
  issue(1, 1);
  int buf = 0;
  for (int t = 0; t < T; ++t) {
    if (t + 2 < T) {
      int nb = buf - 1; if (nb < 0) nb = 2;
      issue(t + 2, nb);
      asm volatile("s_waitcnt vmcnt(8)" ::: "memory");
    } else if (t + 1 < T) {
      asm volatile("s_waitcnt vmcnt(4)" ::: "memory");
    } else {
      asm volatile("s_waitcnt vmcnt(0)" ::: "memory");
    }
    asm volatile("s_barrier" ::: "memory");
    short8 af[4], bfr[4];
#pragma unroll
    for (int mi = 0; mi < 4; ++mi)
      af[mi] = *(const short8*)(As[buf] + (quad*128 + wm*64 + mi*16 + l16)*8);
#pragma unroll
    for (int ni = 0; ni < 4; ++ni)
      bfr[ni] = *(const short8*)(Bs[buf] + (quad*128 + wn*64 + ni*16 + l16)*8);
#pragma unroll
    for (int mi = 0; mi < 4; ++mi)
#pragma unroll
      for (int ni = 0; ni < 4; ++ni)
        acc[mi][ni] = __builtin_amdgcn_mfma_f32_16x16x32_bf16(af[mi], bfr[ni], acc[mi][ni], 0, 0, 0);
    asm volatile("s_barrier" ::: "memory");
    buf = buf + 1; if (buf > 2) buf = 0;
  }

  const int n064 = n0 + wn * 64;
  if (isq) {
    const int h = n064 / QHD;
    const bool ropew = (n064 % QHD) == 128;
    if (!ropew) {
      const int dbase = n064 - h * QHD;
#pragma unroll
      for (int mi = 0; mi < 4; ++mi)
#pragma unroll
        for (int ni = 0; ni < 4; ++ni) {
          int d = dbase + ni*16 + l16;
#pragma unroll
          for (int r = 0; r < 4; ++r) {
            int row = m0 + wm*64 + mi*16 + quad*4 + r;
            qhm[((size_t)h*SEQ + row)*QHD + d] = f2bf(acc[mi][ni][r] * SCALE_L2E);
          }
        }
    } else {
#pragma unroll
      for (int ni = 0; ni < 2; ++ni) {
        int i = ni*16 + l16;                     // 0..31
        float fr = powf(10000.0f, -(float)i / 32.0f);
#pragma unroll
        for (int mi = 0; mi < 4; ++mi) {
#pragma unroll
          for (int r = 0; r < 4; ++r) {
            int row = m0 + wm*64 + mi*16 + quad*4 + r;
            float ang = (float)row * fr;
            float cv, sv; __sincosf(ang, &sv, &cv);
            float x1 = acc[mi][ni][r], x2 = acc[mi][ni+2][r];
            qhm[((size_t)h*SEQ + row)*QHD + 128 + i] = f2bf((x1*cv - x2*sv) * SCALE_L2E);
            qhm[((size_t)h*SEQ + row)*QHD + 160 + i] = f2bf((x2*cv + x1*sv) * SCALE_L2E);
          }
        }
      }
    }
  } else {
    const bool isv = (n064 & 128) != 0;
    if (!isv) {
#pragma unroll
      for (int mi = 0; mi < 4; ++mi)
#pragma unroll
        for (int ni = 0; ni < 4; ++ni) {
          int col = n064 + ni*16 + l16;
          int h = col >> 8, d = col & 127;
#pragma unroll
          for (int r = 0; r < 4; ++r) {
            int row = m0 + wm*64 + mi*16 + quad*4 + r;
            knope[((size_t)h*SEQ + row)*NOPE + d] = f2bf(acc[mi][ni][r]);
          }
        }
    } else {
#pragma unroll
      for (int mi = 0; mi < 4; ++mi)
#pragma unroll
        for (int ni = 0; ni < 4; ++ni) {
          int col = n064 + ni*16 + l16;
          int h = col >> 8, dv = (col & 255) - 128;
          int row = m0 + wm*64 + mi*16 + quad*4;
          short4v pk;
          pk.x = f2bf(acc[mi][ni][0]); pk.y = f2bf(acc[mi][ni][1]);
          pk.z = f2bf(acc[mi][ni][2]); pk.w = f2bf(acc[mi][ni][3]);
          *(short4v*)(vTd + (size_t)(h*128 + dv)*SEQ + row) = pk;
        }
    }
  }
}

// ---------------- merged RMS norms + rope_k ----------------
__global__ __launch_bounds__(256) void k_rms2(
    const float* __restrict__ qlat, const float* __restrict__ q_a_ln,
    short* __restrict__ qlatn,
    const float* __restrict__ kvlp, const float* __restrict__ kv_a_ln,
    short* __restrict__ kvln, short* __restrict__ kpe)
{
  int b = blockIdx.x;
  __shared__ float red[4];
  if (b < SEQ) {
    int row = b;
    const float* xr = qlat + (size_t)row * QLR;
    float s = 0.f;
    for (int i = threadIdx.x; i < QLR; i += 256) { float v = xr[i]; s += v*v; }
#pragma unroll
    for (int off = 1; off < 64; off <<= 1) s += __shfl_xor(s, off);
    if ((threadIdx.x & 63) == 0) red[threadIdx.x >> 6] = s;
    __syncthreads();
    float inv = rsqrtf((red[0]+red[1]+red[2]+red[3]) / (float)QLR + 1e-6f);
    for (int i = threadIdx.x; i < QLR; i += 256)
      qlatn[(size_t)row * QLR + i] = f2bf(xr[i] * inv * q_a_ln[i]);
  } else {
    int row = b - SEQ;
    const float* xr = kvlp + (size_t)row * KVAW_N;
    float s = 0.f;
    for (int i = threadIdx.x; i < KVLR; i += 256) { float v = xr[i]; s += v*v; }
#pragma unroll
    for (int off = 1; off < 64; off <<= 1) s += __shfl_xor(s, off);
    if ((threadIdx.x & 63) == 0) red[threadIdx.x >> 6] = s;
    __syncthreads();
    float inv = rsqrtf((red[0]+red[1]+red[2]+red[3]) / (float)KVLR + 1e-6f);
    for (int i = threadIdx.x; i < KVLR; i += 256)
      kvln[(size_t)row * KVLR + i] = f2bf(xr[i] * inv * kv_a_ln[i]);
    if (threadIdx.x < 32) {
      int i = threadIdx.x;
      float ang = (float)row * powf(10000.0f, -(float)i / 32.0f);
      float cv, sv; __sincosf(ang, &sv, &cv);
      float x1 = xr[KVLR + i], x2 = xr[KVLR + 32 + i];
      kpe[(size_t)row * ROPED + i]      = f2bf(x1*cv - x2*sv);
      kpe[(size_t)row * ROPED + i + 32] = f2bf(x2*cv + x1*sv);
    }
  }
}

// ---------------- attention: per-wave prefetch pipeline, chunk=32 ----------------
__global__ __launch_bounds__(256, 2) void k_attn6(
    const short* __restrict__ qhm,   // [NH][SEQ][192] prescaled
    const short* __restrict__ knope, // [NH][SEQ][128]
    const short* __restrict__ kpe,   // [SEQ][64]
    const short* __restrict__ vT,    // [NH*128][SEQ]
    short* __restrict__ Opart,       // [NSEG][SEQ][NOV]
    float2* __restrict__ mlb)        // [NSEG][SEQ][NH]
{
  __shared__ short Pl[4 * 32 * 40];
  const int tid = threadIdx.x;
  const int lane = tid & 63, w = tid >> 6;
  const int quad = lane >> 4, l16 = lane & 15;
  const int b = blockIdx.x;
  const int h = b & 15;                   // head -> XCD class for L2 locality
  const int r = (b >> 4) * 4 + w;         // 0..159
  int qw, seg;
  if (r < 16)      { qw = r; seg = 0; }
  else if (r < 48) { int x = r - 16; qw = 16 + (x >> 1); seg = x & 1; }
  else if (r < 96) { int x = r - 48; int d3 = x / 3; qw = 32 + d3; seg = x - 3*d3; }
  else             { int x = r - 96; qw = 48 + (x >> 2); seg = x & 3; }
  const int qws = qw * 32;
  const int tc = qw + 1;                  // chunks of 32 kv
  const int cs = seg * 16;
  const int cend = (tc < cs + 16) ? tc : (cs + 16);
  short* Plw = Pl + w * (32 * 40);

  const short* qbase = qhm + (size_t)h * SEQ * QHD;
  const short* kbase = knope + (size_t)h * SEQ * NOPE;
  const short* vbase = vT + (size_t)h * 128 * SEQ;

  short8 qf[2][6];
#pragma unroll
  for (int nt = 0; nt < 2; ++nt)
#pragma unroll
    for (int ks = 0; ks < 6; ++ks)
      qf[nt][ks] = *(const short8*)(qbase + (size_t)(qws + nt*16 + l16)*QHD + ks*32 + quad*8);

  floatx4 oacc[8][2] = {};
  float m_i[2] = {-1e30f, -1e30f}, l_i[2] = {0.f, 0.f};

  auto loadKn = [&](int kc, short8* kn) {
    int kv0 = kc * 32;
#pragma unroll
    for (int mt = 0; mt < 2; ++mt) {
      const short* kr = kbase + (size_t)(kv0 + mt*16 + l16) * NOPE;
#pragma unroll
      for (int ks = 0; ks < 4; ++ks) kn[mt*4 + ks] = *(const short8*)(kr + ks*32 + quad*8);
    }
  };

  auto body = [&](int kc, short8* kcur, short8* knext) {
    const int kv0 = kc * 32;
    short8 krope[4];
#pragma unroll
    for (int mt = 0; mt < 2; ++mt) {
      const short* rr2 = kpe + (size_t)(kv0 + mt*16 + l16) * ROPED;
      krope[mt*2]     = *(const short8*)(rr2 + quad*8);
      krope[mt*2 + 1] = *(const short8*)(rr2 + 32 + quad*8);
    }
    short8 vf[8];
#pragma unroll
    for (int dt = 0; dt < 8; ++dt)
      vf[dt] = *(const short8*)(vbase + (size_t)(dt*16 + l16)*SEQ + kv0 + quad*8);
    int kn2 = (kc + 1 < cend) ? kc + 1 : kc;
    loadKn(kn2, knext);

    floatx4 s[2][2] = {};
#pragma unroll
    for (int ks = 0; ks < 4; ++ks)
#pragma unroll
      for (int mt = 0; mt < 2; ++mt) {
        s[mt][0] = __builtin_amdgcn_mfma_f32_16x16x32_bf16(kcur[mt*4+ks], qf[0][ks], s[mt][0], 0, 0, 0);
        s[mt][1] = __builtin_amdgcn_mfma_f32_16x16x32_bf16(kcur[mt*4+ks], qf[1][ks], s[mt][1], 0, 0, 0);
      }
#pragma unroll
    for (int ks = 4; ks < 6; ++ks)
#pragma unroll
      for (int mt = 0; mt < 2; ++mt) {
        s[mt][0] = __builtin_amdgcn_mfma_f32_16x16x32_bf16(krope[mt*2+ks-4], qf[0][ks], s[mt][0], 0, 0, 0);
        s[mt][1] = __builtin_amdgcn_mfma_f32_16x16x32_bf16(krope[mt*2+ks-4], qf[1][ks], s[mt][1], 0, 0, 0);
      }

    const bool diag = (kv0 + 32 > qws);
#pragma unroll
    for (int nt = 0; nt < 2; ++nt) {
      const int qg = qws + nt*16 + l16;
      float mx = -1e30f;
#pragma unroll
      for (int mt = 0; mt < 2; ++mt)
#pragma unroll
        for (int rr = 0; rr < 4; ++rr) {
          float v = s[mt][nt][rr];
          if (diag) {
            int kvg = kv0 + mt*16 + quad*4 + rr;
            v = (kvg <= qg) ? v : -1e30f;
            s[mt][nt][rr] = v;
          }
          mx = fmaxf(mx, v);
        }
      mx = fmaxf(mx, __shfl_xor(mx, 16));
      mx = fmaxf(mx, __shfl_xor(mx, 32));
      float mnew = fmaxf(m_i[nt], mx);
      float alpha = exp2f(m_i[nt] - mnew);
      m_i[nt] = mnew;
      float ssum = 0.f;
#pragma unroll
      for (int mt = 0; mt < 2; ++mt) {
        float p0 = exp2f(s[mt][nt][0] - mnew);
        float p1 = exp2f(s[mt][nt][1] - mnew);
        float p2 = exp2f(s[mt][nt][2] - mnew);
        float p3 = exp2f(s[mt][nt][3] - mnew);
        ssum += (p0 + p1) + (p2 + p3);
        short4v pk; pk.x = f2bf(p0); pk.y = f2bf(p1); pk.z = f2bf(p2); pk.w = f2bf(p3);
        *(short4v*)(Plw + (nt*16 + l16)*40 + mt*16 + quad*4) = pk;
      }
      ssum += __shfl_xor(ssum, 16);
      ssum += __shfl_xor(ssum, 32);
      l_i[nt] = l_i[nt] * alpha + ssum;
#pragma unroll
      for (int dt = 0; dt < 8; ++dt)
#pragma unroll
        for (int rr = 0; rr < 4; ++rr) oacc[dt][nt][rr] *= alpha;
    }

    short8 pf[2];
#pragma unroll
    for (int nt = 0; nt < 2; ++nt)
      pf[nt] = *(const short8*)(Plw + (nt*16 + l16)*40 + quad*8);
#pragma unroll
    for (int dt = 0; dt < 8; ++dt) {
      oacc[dt][0] = __builtin_amdgcn_mfma_f32_16x16x32_bf16(vf[dt], pf[0], oacc[dt][0], 0, 0, 0);
      oacc[dt][1] = __builtin_amdgcn_mfma_f32_16x16x32_bf16(vf[dt], pf[1], oacc[dt][1], 0, 0, 0);
    }
  };

  short8 kna[8], knb[8];
  loadKn(cs, kna);
  for (int kc = cs; kc < cend; kc += 2) {
    body(kc, kna, knb);
    if (kc + 1 < cend) body(kc + 1, knb, kna);
  }

#pragma unroll
  for (int nt = 0; nt < 2; ++nt) {
    float inv = (l_i[nt] > 0.f) ? 1.f / l_i[nt] : 0.f;
    int q = qws + nt*16 + l16;
    if (quad == 0)
      mlb[((size_t)seg * SEQ + q) * NH + h] = make_float2(m_i[nt], l_i[nt]);
#pragma unroll
    for (int dt = 0; dt < 8; ++dt) {
      short4v pk;
      pk.x = f2bf(oacc[dt][nt][0] * inv);
      pk.y = f2bf(oacc[dt][nt][1] * inv);
      pk.z = f2bf(oacc[dt][nt][2] * inv);
      pk.w = f2bf(oacc[dt][nt][3] * inv);
      *(short4v*)(Opart + ((size_t)seg * SEQ + q) * NOV + h * VH + dt*16 + quad*4) = pk;
    }
  }
}

// ---------------- split-KV combiner ----------------
__global__ __launch_bounds__(256) void k_comb(
    const short* __restrict__ Opart, const float2* __restrict__ mlb,
    short* __restrict__ ob)
{
  int q = blockIdx.x;
  int hd0 = threadIdx.x * 8;
  int h = hd0 >> 7;
  int nact = (q >> 9) + 1;
  float2 mlv[NSEG];
  float M = -1e30f;
  for (int s = 0; s < nact; ++s) {
    mlv[s] = mlb[((size_t)s * SEQ + q) * NH + h];
    M = fmaxf(M, mlv[s].x);
  }
  float wgt[NSEG]; float L = 0.f;
  for (int s = 0; s < nact; ++s) {
    wgt[s] = mlv[s].y * exp2f(mlv[s].x - M);
    L += wgt[s];
  }
  float invL = 1.0f / L;
  float acc[8] = {};
  for (int s = 0; s < nact; ++s) {
    short8 o = *(const short8*)(Opart + ((size_t)s * SEQ + q) * NOV + hd0);
    float ws = wgt[s] * invL;
#pragma unroll
    for (int j = 0; j < 8; ++j) acc[j] += ws * bf2f(o[j]);
  }
  short8 rr;
#pragma unroll
  for (int j = 0; j < 8; ++j) rr[j] = f2bf(acc[j]);
  *(short8*)(ob + (size_t)q * NOV + hd0) = rr;
}

// ---------------- launch ----------------
extern "C" void kernel_launch(void* const* d_in, const int* in_sizes, int n_in,
                              void* d_out, int out_size, void* d_ws, size_t ws_size,
                              hipStream_t stream) {
  const float* hs      = (const float*)d_in[0];
  const float* q_a_w   = (const float*)d_in[1];
  const float* q_a_ln  = (const float*)d_in[2];
  const float* q_b_w   = (const float*)d_in[3];
  const float* kv_a_w  = (const float*)d_in[4];
  const float* kv_a_ln = (const float*)d_in[5];
  const float* kv_b_w  = (const float*)d_in[6];
  const float* o_w     = (const float*)d_in[7];
  float* out = (float*)d_out;

  char* ws = (char*)d_ws;
  size_t off = 0;
  auto alloc = [&](size_t bytes) {
    void* p = ws + off;
    off += (bytes + 255) & ~(size_t)255;
    return p;
  };
  const size_t MB = 1u << 20;
  short* hs_b   = (short*)alloc((size_t)SEQ * H * 2);
  short* wab    = (short*)alloc((size_t)(QLR + KVAW_N) * H * 2);  // stacked q_a|kv_a
  short* qbw_b  = (short*)alloc((size_t)NQH * QLR * 2);
  short* kvbw_b = (short*)alloc((size_t)NKVC * KVLR * 2);
  short* ow_b   = (short*)alloc((size_t)H * NOV * 2);
  short* qhm    = (short*)alloc((size_t)NH * SEQ * QHD * 2);   // head-major q
  short* kpeb   = (short*)alloc((size_t)SEQ * ROPED * 2);
  short* knope  = (short*)alloc((size_t)NH * SEQ * NOPE * 2);  // head-major k
  short* vT     = (short*)alloc((size_t)NH * VH * SEQ * 2);
  short* attnb  = (short*)alloc((size_t)SEQ * NOV * 2);
  char* R = (char*)alloc(36 * MB);
  float* qlat  = (float*)R;                 // 12.6 MB (phase 1-2)
  short* qlatn = (short*)(R + 13 * MB);     // 6.3 MB  (phase 2-3)
  short* kvln  = (short*)(R + 20 * MB);     // 2.1 MB  (phase 2-3)
  float* kvlp  = (float*)(R + 24 * MB);     // 4.7 MB  (phase 1-2)
  short* Opart = (short*)R;                 // 33.6 MB (attn)
  float2* mlb  = (float2*)(R + 34 * MB);    // 1.05 MB (attn)

  CvtArgs ca;
  ca.src[0] = hs;     ca.dst[0] = hs_b;
  ca.src[1] = q_a_w;  ca.dst[1] = wab;
  ca.src[2] = kv_a_w; ca.dst[2] = wab + (size_t)QLR * H;
  ca.src[3] = q_b_w;  ca.dst[3] = qbw_b;
  ca.src[4] = kv_b_w; ca.dst[4] = kvbw_b;
  ca.src[5] = o_w;    ca.dst[5] = ow_b;
  int sizes4[6] = { SEQ*H/4, QLR*H/4, KVAW_N*H/4, NQH*QLR/4, NKVC*KVLR/4, H*NOV/4 };
  ca.cum[0] = 0;
  for (int i = 0; i < 6; ++i) ca.cum[i+1] = ca.cum[i] + sizes4[i];
  k_cvt_all<<<2048, 256, 0, stream>>>(ca, ca.cum[6]);

  // GEMM1: [qlat | kvlp] = hs @ [q_a_w; kv_a_w]^T  (N=2112, 16x33=528 blocks)
  k_gemm64<1><<<dim3(SEQ/128, (QLR + KVAW_N)/64), 256, 0, stream>>>(
      hs_b, wab, qlat, kvlp, QLR + KVAW_N, H);
  // merged rms + rope_k
  k_rms2<<<2*SEQ, 256, 0, stream>>>(qlat, q_a_ln, qlatn, kvlp, kv_a_ln, kvln, kpeb);
  // GEMM2: q_b (fused rope+prescale -> qhm) + kv_b (-> knope, vT)  (896 blocks)
  k_gemm2<<<896, 256, 0, stream>>>(qlatn, qbw_b, kvln, kvbw_b, qhm, knope, vT);
  // attention + combine
  k_attn6<<<640, 256, 0, stream>>>(qhm, knope, kpeb, vT, Opart, mlb);
  k_comb<<<SEQ, 256, 0, stream>>>(Opart, mlb, attnb);
  // GEMM3: out = attn @ o_w^T  (16x32=512 blocks)
  k_gemm64<0><<<dim3(SEQ/128, H/64), 256, 0, stream>>>(
      attnb, ow_b, out, nullptr, H, NOV);
}

// Round 7
// 492.906 us; speedup vs baseline: 1.3426x; 1.0249x over previous
//
#include <hip/hip_runtime.h>
#include <cstdint>

#define H 2048
#define NH 16
#define QLR 1536
#define KVLR 512
#define NOPE 128
#define ROPED 64
#define VH 128
#define QHD 192
#define SEQ 2048
#define NQH (NH*QHD)        // 3072
#define NKVC (NH*(NOPE+VH)) // 4096
#define NOV (NH*VH)         // 2048
#define KVAW_N (KVLR+ROPED) // 576
#define SCALE_L2E 0.10411755f   // 192^-0.5 * log2(e)
#define NSEG 4

typedef __attribute__((ext_vector_type(8))) short short8;
typedef __attribute__((ext_vector_type(4))) short short4v;
typedef __attribute__((ext_vector_type(4))) float floatx4;

__device__ __forceinline__ short f2bf(float x) {
  unsigned u = __builtin_bit_cast(unsigned, x);
  unsigned r = (u + 0x7FFFu + ((u >> 16) & 1u)) >> 16;
  return (short)(unsigned short)r;
}
__device__ __forceinline__ float bf2f(short s) {
  unsigned u = ((unsigned)(unsigned short)s) << 16;
  return __builtin_bit_cast(float, u);
}
__device__ __forceinline__ void g2l16(const void* g, void* l) {
  __builtin_amdgcn_global_load_lds(
      (const __attribute__((address_space(1))) void*)(uintptr_t)(g),
      (__attribute__((address_space(3))) void*)(uintptr_t)(l),
      16, 0, 0);
}

// ---------------- fused fp32 -> bf16 convert ----------------
struct CvtArgs {
  const float* src[6];
  short* dst[6];
  int cum[7];
};
__global__ __launch_bounds__(256) void k_cvt_all(CvtArgs a, int total4) {
  int stride = gridDim.x * 256;
  for (int i = blockIdx.x * 256 + threadIdx.x; i < total4; i += stride) {
    int j = 0;
#pragma unroll
    for (int t = 1; t < 6; ++t) j += (i >= a.cum[t]);
    int loc = i - a.cum[j];
    float4 v = ((const float4*)a.src[j])[loc];
    short4v o;
    o.x = f2bf(v.x); o.y = f2bf(v.y); o.z = f2bf(v.z); o.w = f2bf(v.w);
    ((short4v*)a.dst[j])[loc] = o;
  }
}

// ---------------- BN=64 pipelined NT GEMM (128x64 tile, 3-ring) ----------------
template<int EPI>
__global__ __launch_bounds__(256) void k_gemm64(
    const short* __restrict__ A, const short* __restrict__ B,
    float* __restrict__ C, float* __restrict__ C2, int N, int K)
{
  __shared__ short As[3][4096];   // 128 x 32
  __shared__ short Bs[3][2048];   // 64 x 32
  const int tid = threadIdx.x;
  const int lane = tid & 63;
  const int w = tid >> 6;
  const int wm = w & 1, wn = w >> 1;
  const int quad = lane >> 4, l16 = lane & 15;
  const int m0 = blockIdx.x * 128, n0 = blockIdx.y * 64;
  const int T = K >> 5;

  floatx4 acc[4][2] = {};

  auto issue = [&](int t, int buf) {
#pragma unroll
    for (int i = 0; i < 2; ++i) {
      int c = i*256 + tid;
      int row = c & 127, koct = c >> 7;
      g2l16(A + (size_t)(m0 + row)*K + t*32 + koct*8, As[buf] + (koct*128 + row)*8);
    }
    { int c = tid; int row = c & 63, koct = c >> 6;
      g2l16(B + (size_t)(n0 + row)*K + t*32 + koct*8, Bs[buf] + (koct*64 + row)*8); }
  };

  issue(0, 0);
  issue(1, 1);
  int buf = 0;
  for (int t = 0; t < T; ++t) {
    if (t + 2 < T) {
      int nb = buf - 1; if (nb < 0) nb = 2;
      issue(t + 2, nb);
      asm volatile("s_waitcnt vmcnt(6)" ::: "memory");
    } else if (t + 1 < T) {
      asm volatile("s_waitcnt vmcnt(3)" ::: "memory");
    } else {
      asm volatile("s_waitcnt vmcnt(0)" ::: "memory");
    }
    asm volatile("s_barrier" ::: "memory");
    short8 af[4], bfr[2];
#pragma unroll
    for (int mi = 0; mi < 4; ++mi)
      af[mi] = *(const short8*)(As[buf] + (quad*128 + wm*64 + mi*16 + l16)*8);
#pragma unroll
    for (int ni = 0; ni < 2; ++ni)
      bfr[ni] = *(const short8*)(Bs[buf] + (quad*64 + wn*32 + ni*16 + l16)*8);
#pragma unroll
    for (int mi = 0; mi < 4; ++mi)
#pragma unroll
      for (int ni = 0; ni < 2; ++ni)
        acc[mi][ni] = __builtin_amdgcn_mfma_f32_16x16x32_bf16(af[mi], bfr[ni], acc[mi][ni], 0, 0, 0);
    asm volatile("s_barrier" ::: "memory");
    buf = buf + 1; if (buf > 2) buf = 0;
  }

#pragma unroll
  for (int mi = 0; mi < 4; ++mi) {
#pragma unroll
    for (int ni = 0; ni < 2; ++ni) {
      int col = n0 + wn*32 + ni*16 + l16;
#pragma unroll
      for (int r = 0; r < 4; ++r) {
        int row = m0 + wm*64 + mi*16 + quad*4 + r;
        if (EPI == 0) {
          C[(size_t)row*N + col] = acc[mi][ni][r];
        } else {
          if (col < QLR) C[(size_t)row*QLR + col] = acc[mi][ni][r];
          else           C2[(size_t)row*KVAW_N + (col - QLR)] = acc[mi][ni][r];
        }
      }
    }
  }
}

// ---------------- merged q_b + kv_b GEMM (BN=128, 3-ring) ----------------
__global__ __launch_bounds__(256) void k_gemm2(
    const short* __restrict__ qlatn, const short* __restrict__ qbw,
    const short* __restrict__ kvln,  const short* __restrict__ kvbw,
    short* __restrict__ qhm, short* __restrict__ knope, short* __restrict__ vTd)
{
  __shared__ short As[3][4096];
  __shared__ short Bs[3][4096];
  const int tid = threadIdx.x;
  const int lane = tid & 63;
  const int w = tid >> 6;
  const int wm = w & 1, wn = w >> 1;
  const int quad = lane >> 4, l16 = lane & 15;
  int bid = blockIdx.x;
  const short *A, *B; int K, m0, n0; bool isq;
  if (bid < 384) { isq = true;  A = qlatn; B = qbw;  K = QLR;
    m0 = (bid & 15) * 128; n0 = (bid >> 4) * 128; }
  else { int b2 = bid - 384; isq = false; A = kvln; B = kvbw; K = KVLR;
    m0 = (b2 & 15) * 128; n0 = (b2 >> 4) * 128; }
  const int T = K >> 5;

  floatx4 acc[4][4] = {};

  auto issue = [&](int t, int buf) {
#pragma unroll
    for (int i = 0; i < 2; ++i) {
      int c = i*256 + tid;
      int row = c & 127, koct = c >> 7;
      g2l16(A + (size_t)(m0 + row)*K + t*32 + koct*8, As[buf] + (koct*128 + row)*8);
      g2l16(B + (size_t)(n0 + row)*K + t*32 + koct*8, Bs[buf] + (koct*128 + row)*8);
    }
  };

  issue(0, 0);
  issue(1, 1);
  int buf = 0;
  for (int t = 0; t < T; ++t) {
    if (t + 2 < T) {
      int nb = buf - 1; if (nb < 0) nb = 2;
      issue(t + 2, nb);
      asm volatile("s_waitcnt vmcnt(8)" ::: "memory");
    } else if (t + 1 < T) {
      asm volatile("s_waitcnt vmcnt(4)" ::: "memory");
    } else {
      asm volatile("s_waitcnt vmcnt(0)" ::: "memory");
    }
    asm volatile("s_barrier" ::: "memory");
    short8 af[4], bfr[4];
#pragma unroll
    for (int mi = 0; mi < 4; ++mi)
      af[mi] = *(const short8*)(As[buf] + (quad*128 + wm*64 + mi*16 + l16)*8);
#pragma unroll
    for (int ni = 0; ni < 4; ++ni)
      bfr[ni] = *(const short8*)(Bs[buf] + (quad*128 + wn*64 + ni*16 + l16)*8);
#pragma unroll
    for (int mi = 0; mi < 4; ++mi)
#pragma unroll
      for (int ni = 0; ni < 4; ++ni)
        acc[mi][ni] = __builtin_amdgcn_mfma_f32_16x16x32_bf16(af[mi], bfr[ni], acc[mi][ni], 0, 0, 0);
    asm volatile("s_barrier" ::: "memory");
    buf = buf + 1; if (buf > 2) buf = 0;
  }

  const int n064 = n0 + wn * 64;
  if (isq) {
    const int h = n064 / QHD;
    const bool ropew = (n064 % QHD) == 128;
    if (!ropew) {
      const int dbase = n064 - h * QHD;
#pragma unroll
      for (int mi = 0; mi < 4; ++mi)
#pragma unroll
        for (int ni = 0; ni < 4; ++ni) {
          int d = dbase + ni*16 + l16;
#pragma unroll
          for (int r = 0; r < 4; ++r) {
            int row = m0 + wm*64 + mi*16 + quad*4 + r;
            qhm[((size_t)h*SEQ + row)*QHD + d] = f2bf(acc[mi][ni][r] * SCALE_L2E);
          }
        }
    } else {
#pragma unroll
      for (int ni = 0; ni < 2; ++ni) {
        int i = ni*16 + l16;                     // 0..31
        float fr = powf(10000.0f, -(float)i / 32.0f);
#pragma unroll
        for (int mi = 0; mi < 4; ++mi) {
#pragma unroll
          for (int r = 0; r < 4; ++r) {
            int row = m0 + wm*64 + mi*16 + quad*4 + r;
            float ang = (float)row * fr;
            float cv, sv; __sincosf(ang, &sv, &cv);
            float x1 = acc[mi][ni][r], x2 = acc[mi][ni+2][r];
            qhm[((size_t)h*SEQ + row)*QHD + 128 + i] = f2bf((x1*cv - x2*sv) * SCALE_L2E);
            qhm[((size_t)h*SEQ + row)*QHD + 160 + i] = f2bf((x2*cv + x1*sv) * SCALE_L2E);
          }
        }
      }
    }
  } else {
    const bool isv = (n064 & 128) != 0;
    if (!isv) {
#pragma unroll
      for (int mi = 0; mi < 4; ++mi)
#pragma unroll
        for (int ni = 0; ni < 4; ++ni) {
          int col = n064 + ni*16 + l16;
          int h = col >> 8, d = col & 127;
#pragma unroll
          for (int r = 0; r < 4; ++r) {
            int row = m0 + wm*64 + mi*16 + quad*4 + r;
            knope[((size_t)h*SEQ + row)*NOPE + d] = f2bf(acc[mi][ni][r]);
          }
        }
    } else {
#pragma unroll
      for (int mi = 0; mi < 4; ++mi)
#pragma unroll
        for (int ni = 0; ni < 4; ++ni) {
          int col = n064 + ni*16 + l16;
          int h = col >> 8, dv = (col & 255) - 128;
          int row = m0 + wm*64 + mi*16 + quad*4;
          short4v pk;
          pk.x = f2bf(acc[mi][ni][0]); pk.y = f2bf(acc[mi][ni][1]);
          pk.z = f2bf(acc[mi][ni][2]); pk.w = f2bf(acc[mi][ni][3]);
          *(short4v*)(vTd + (size_t)(h*128 + dv)*SEQ + row) = pk;
        }
    }
  }
}

// ---------------- merged RMS norms + rope_k ----------------
__global__ __launch_bounds__(256) void k_rms2(
    const float* __restrict__ qlat, const float* __restrict__ q_a_ln,
    short* __restrict__ qlatn,
    const float* __restrict__ kvlp, const float* __restrict__ kv_a_ln,
    short* __restrict__ kvln, short* __restrict__ kpe)
{
  int b = blockIdx.x;
  __shared__ float red[4];
  if (b < SEQ) {
    int row = b;
    const float* xr = qlat + (size_t)row * QLR;
    float s = 0.f;
    for (int i = threadIdx.x; i < QLR; i += 256) { float v = xr[i]; s += v*v; }
#pragma unroll
    for (int off = 1; off < 64; off <<= 1) s += __shfl_xor(s, off);
    if ((threadIdx.x & 63) == 0) red[threadIdx.x >> 6] = s;
    __syncthreads();
    float inv = rsqrtf((red[0]+red[1]+red[2]+red[3]) / (float)QLR + 1e-6f);
    for (int i = threadIdx.x; i < QLR; i += 256)
      qlatn[(size_t)row * QLR + i] = f2bf(xr[i] * inv * q_a_ln[i]);
  } else {
    int row = b - SEQ;
    const float* xr = kvlp + (size_t)row * KVAW_N;
    float s = 0.f;
    for (int i = threadIdx.x; i < KVLR; i += 256) { float v = xr[i]; s += v*v; }
#pragma unroll
    for (int off = 1; off < 64; off <<= 1) s += __shfl_xor(s, off);
    if ((threadIdx.x & 63) == 0) red[threadIdx.x >> 6] = s;
    __syncthreads();
    float inv = rsqrtf((red[0]+red[1]+red[2]+red[3]) / (float)KVLR + 1e-6f);
    for (int i = threadIdx.x; i < KVLR; i += 256)
      kvln[(size_t)row * KVLR + i] = f2bf(xr[i] * inv * kv_a_ln[i]);
    if (threadIdx.x < 32) {
      int i = threadIdx.x;
      float ang = (float)row * powf(10000.0f, -(float)i / 32.0f);
      float cv, sv; __sincosf(ang, &sv, &cv);
      float x1 = xr[KVLR + i], x2 = xr[KVLR + 32 + i];
      kpe[(size_t)row * ROPED + i]      = f2bf(x1*cv - x2*sv);
      kpe[(size_t)row * ROPED + i + 32] = f2bf(x2*cv + x1*sv);
    }
  }
}

// ---------------- attention: chunk=128, one softmax per chunk ----------------
// 2560 balanced wave-segments (<=4 chunks of 128 kv), longest first.
// K/V frags direct from global; wave-private P in LDS (32q x 128kv, pad->136).
__global__ __launch_bounds__(256) void k_attn7(
    const short* __restrict__ qhm,   // [NH][SEQ][192] prescaled
    const short* __restrict__ knope, // [NH][SEQ][128]
    const short* __restrict__ kpe,   // [SEQ][64]
    const short* __restrict__ vT,    // [NH*128][SEQ]
    short* __restrict__ Opart,       // [NSEG][SEQ][NOV]
    float2* __restrict__ mlb)        // [NSEG][SEQ][NH]
{
  __shared__ short Pl[4][32 * 136];
  const int tid = threadIdx.x;
  const int lane = tid & 63, w = tid >> 6;
  const int quad = lane >> 4, l16 = lane & 15;
  const int b = blockIdx.x;
  const int h = b & 15;                     // head -> L2 locality
  const int r = (39 - (b >> 4)) * 4 + w;    // 0..159, longest segs first
  int qw, seg;
  if (r < 16)      { qw = r; seg = 0; }
  else if (r < 48) { int x = r - 16; qw = 16 + (x >> 1); seg = x & 1; }
  else if (r < 96) { int x = r - 48; int d3 = x / 3; qw = 32 + d3; seg = x - 3*d3; }
  else             { int x = r - 96; qw = 48 + (x >> 2); seg = x & 3; }
  const int qws = qw * 32;
  const int tc = (qw + 4) >> 2;             // chunks of 128 kv for full q-range
  const int cs = seg * 4;
  const int cend = (tc < cs + 4) ? tc : (cs + 4);
  short* Plw = Pl[w];

  const short* qbase = qhm + (size_t)h * SEQ * QHD;
  const short* kbase = knope + (size_t)h * SEQ * NOPE;
  const short* vbase = vT + (size_t)h * 128 * SEQ;

  short8 qf[2][6];
#pragma unroll
  for (int nt = 0; nt < 2; ++nt)
#pragma unroll
    for (int ks = 0; ks < 6; ++ks)
      qf[nt][ks] = *(const short8*)(qbase + (size_t)(qws + nt*16 + l16)*QHD + ks*32 + quad*8);

  floatx4 oacc[8][2] = {};
  float m_i[2] = {-1e30f, -1e30f}, l_i[2] = {0.f, 0.f};

  for (int kc = cs; kc < cend; ++kc) {
    const int kv0 = kc * 128;

    // ---- S^T over 8 sub-tiles of 16 kv ----
    floatx4 s[8][2] = {};
#pragma unroll
    for (int mt = 0; mt < 8; ++mt) {
      const short* kr = kbase + (size_t)(kv0 + mt*16 + l16) * NOPE;
      const short* rr2 = kpe + (size_t)(kv0 + mt*16 + l16) * ROPED;
      short8 kf0 = *(const short8*)(kr + quad*8);
      short8 kf1 = *(const short8*)(kr + 32 + quad*8);
      short8 kf2 = *(const short8*)(kr + 64 + quad*8);
      short8 kf3 = *(const short8*)(kr + 96 + quad*8);
      short8 kf4 = *(const short8*)(rr2 + quad*8);
      short8 kf5 = *(const short8*)(rr2 + 32 + quad*8);
      s[mt][0] = __builtin_amdgcn_mfma_f32_16x16x32_bf16(kf0, qf[0][0], s[mt][0], 0, 0, 0);
      s[mt][1] = __builtin_amdgcn_mfma_f32_16x16x32_bf16(kf0, qf[1][0], s[mt][1], 0, 0, 0);
      s[mt][0] = __builtin_amdgcn_mfma_f32_16x16x32_bf16(kf1, qf[0][1], s[mt][0], 0, 0, 0);
      s[mt][1] = __builtin_amdgcn_mfma_f32_16x16x32_bf16(kf1, qf[1][1], s[mt][1], 0, 0, 0);
      s[mt][0] = __builtin_amdgcn_mfma_f32_16x16x32_bf16(kf2, qf[0][2], s[mt][0], 0, 0, 0);
      s[mt][1] = __builtin_amdgcn_mfma_f32_16x16x32_bf16(kf2, qf[1][2], s[mt][1], 0, 0, 0);
      s[mt][0] = __builtin_amdgcn_mfma_f32_16x16x32_bf16(kf3, qf[0][3], s[mt][0], 0, 0, 0);
      s[mt][1] = __builtin_amdgcn_mfma_f32_16x16x32_bf16(kf3, qf[1][3], s[mt][1], 0, 0, 0);
      s[mt][0] = __builtin_amdgcn_mfma_f32_16x16x32_bf16(kf4, qf[0][4], s[mt][0], 0, 0, 0);
      s[mt][1] = __builtin_amdgcn_mfma_f32_16x16x32_bf16(kf4, qf[1][4], s[mt][1], 0, 0, 0);
      s[mt][0] = __builtin_amdgcn_mfma_f32_16x16x32_bf16(kf5, qf[0][5], s[mt][0], 0, 0, 0);
      s[mt][1] = __builtin_amdgcn_mfma_f32_16x16x32_bf16(kf5, qf[1][5], s[mt][1], 0, 0, 0);
    }

    // ---- one softmax pass for all 128 kv ----
    const bool diag = (kv0 + 128 > qws);
#pragma unroll
    for (int nt = 0; nt < 2; ++nt) {
      const int qg = qws + nt*16 + l16;
      float mx = -1e30f;
#pragma unroll
      for (int mt = 0; mt < 8; ++mt)
#pragma unroll
        for (int rr = 0; rr < 4; ++rr) {
          float v = s[mt][nt][rr];
          if (diag) {
            int kvg = kv0 + mt*16 + quad*4 + rr;
            v = (kvg <= qg) ? v : -1e30f;
            s[mt][nt][rr] = v;
          }
          mx = fmaxf(mx, v);
        }
      mx = fmaxf(mx, __shfl_xor(mx, 16));
      mx = fmaxf(mx, __shfl_xor(mx, 32));
      float mnew = fmaxf(m_i[nt], mx);
      float alpha = exp2f(m_i[nt] - mnew);
      m_i[nt] = mnew;
      float ssum = 0.f;
#pragma unroll
      for (int mt = 0; mt < 8; ++mt) {
        float p0 = exp2f(s[mt][nt][0] - mnew);
        float p1 = exp2f(s[mt][nt][1] - mnew);
        float p2 = exp2f(s[mt][nt][2] - mnew);
        float p3 = exp2f(s[mt][nt][3] - mnew);
        ssum += (p0 + p1) + (p2 + p3);
        short4v pk; pk.x = f2bf(p0); pk.y = f2bf(p1); pk.z = f2bf(p2); pk.w = f2bf(p3);
        *(short4v*)(Plw + (nt*16 + l16)*136 + mt*16 + quad*4) = pk;
      }
      ssum += __shfl_xor(ssum, 16);
      ssum += __shfl_xor(ssum, 32);
      l_i[nt] = l_i[nt] * alpha + ssum;
#pragma unroll
      for (int dt = 0; dt < 8; ++dt)
#pragma unroll
        for (int rr = 0; rr < 4; ++rr) oacc[dt][nt][rr] *= alpha;
    }

    // ---- O^T += V^T * P^T over 4 slices of 32 kv ----
#pragma unroll
    for (int sl = 0; sl < 4; ++sl) {
      short8 pf0 = *(const short8*)(Plw + l16*136 + sl*32 + quad*8);
      short8 pf1 = *(const short8*)(Plw + (16 + l16)*136 + sl*32 + quad*8);
#pragma unroll
      for (int dt = 0; dt < 8; ++dt) {
        short8 vf = *(const short8*)(vbase + (size_t)(dt*16 + l16)*SEQ + kv0 + sl*32 + quad*8);
        oacc[dt][0] = __builtin_amdgcn_mfma_f32_16x16x32_bf16(vf, pf0, oacc[dt][0], 0, 0, 0);
        oacc[dt][1] = __builtin_amdgcn_mfma_f32_16x16x32_bf16(vf, pf1, oacc[dt][1], 0, 0, 0);
      }
    }
  }

#pragma unroll
  for (int nt = 0; nt < 2; ++nt) {
    float inv = (l_i[nt] > 0.f) ? 1.f / l_i[nt] : 0.f;
    int q = qws + nt*16 + l16;
    if (quad == 0)
      mlb[((size_t)seg * SEQ + q) * NH + h] = make_float2(m_i[nt], l_i[nt]);
#pragma unroll
    for (int dt = 0; dt < 8; ++dt) {
      short4v pk;
      pk.x = f2bf(oacc[dt][nt][0] * inv);
      pk.y = f2bf(oacc[dt][nt][1] * inv);
      pk.z = f2bf(oacc[dt][nt][2] * inv);
      pk.w = f2bf(oacc[dt][nt][3] * inv);
      *(short4v*)(Opart + ((size_t)seg * SEQ + q) * NOV + h * VH + dt*16 + quad*4) = pk;
    }
  }
}

// ---------------- split-KV combiner ----------------
__global__ __launch_bounds__(256) void k_comb(
    const short* __restrict__ Opart, const float2* __restrict__ mlb,
    short* __restrict__ ob)
{
  int q = blockIdx.x;
  int hd0 = threadIdx.x * 8;
  int h = hd0 >> 7;
  int nact = (q >> 9) + 1;
  float2 mlv[NSEG];
  float M = -1e30f;
  for (int s = 0; s < nact; ++s) {
    mlv[s] = mlb[((size_t)s * SEQ + q) * NH + h];
    M = fmaxf(M, mlv[s].x);
  }
  float wgt[NSEG]; float L = 0.f;
  for (int s = 0; s < nact; ++s) {
    wgt[s] = mlv[s].y * exp2f(mlv[s].x - M);
    L += wgt[s];
  }
  float invL = 1.0f / L;
  float acc[8] = {};
  for (int s = 0; s < nact; ++s) {
    short8 o = *(const short8*)(Opart + ((size_t)s * SEQ + q) * NOV + hd0);
    float ws = wgt[s] * invL;
#pragma unroll
    for (int j = 0; j < 8; ++j) acc[j] += ws * bf2f(o[j]);
  }
  short8 rr;
#pragma unroll
  for (int j = 0; j < 8; ++j) rr[j] = f2bf(acc[j]);
  *(short8*)(ob + (size_t)q * NOV + hd0) = rr;
}

// ---------------- launch ----------------
extern "C" void kernel_launch(void* const* d_in, const int* in_sizes, int n_in,
                              void* d_out, int out_size, void* d_ws, size_t ws_size,
                              hipStream_t stream) {
  const float* hs      = (const float*)d_in[0];
  const float* q_a_w   = (const float*)d_in[1];
  const float* q_a_ln  = (const float*)d_in[2];
  const float* q_b_w   = (const float*)d_in[3];
  const float* kv_a_w  = (const float*)d_in[4];
  const float* kv_a_ln = (const float*)d_in[5];
  const float* kv_b_w  = (const float*)d_in[6];
  const float* o_w     = (const float*)d_in[7];
  float* out = (float*)d_out;

  char* ws = (char*)d_ws;
  size_t off = 0;
  auto alloc = [&](size_t bytes) {
    void* p = ws + off;
    off += (bytes + 255) & ~(size_t)255;
    return p;
  };
  const size_t MB = 1u << 20;
  short* hs_b   = (short*)alloc((size_t)SEQ * H * 2);
  short* wab    = (short*)alloc((size_t)(QLR + KVAW_N) * H * 2);  // stacked q_a|kv_a
  short* qbw_b  = (short*)alloc((size_t)NQH * QLR * 2);
  short* kvbw_b = (short*)alloc((size_t)NKVC * KVLR * 2);
  short* ow_b   = (short*)alloc((size_t)H * NOV * 2);
  short* qhm    = (short*)alloc((size_t)NH * SEQ * QHD * 2);   // head-major q
  short* kpeb   = (short*)alloc((size_t)SEQ * ROPED * 2);
  short* knope  = (short*)alloc((size_t)NH * SEQ * NOPE * 2);  // head-major k
  short* vT     = (short*)alloc((size_t)NH * VH * SEQ * 2);
  short* attnb  = (short*)alloc((size_t)SEQ * NOV * 2);
  char* R = (char*)alloc(36 * MB);
  float* qlat  = (float*)R;                 // 12.6 MB (phase 1-2)
  short* qlatn = (short*)(R + 13 * MB);     // 6.3 MB  (phase 2-3)
  short* kvln  = (short*)(R + 20 * MB);     // 2.1 MB  (phase 2-3)
  float* kvlp  = (float*)(R + 24 * MB);     // 4.7 MB  (phase 1-2)
  short* Opart = (short*)R;                 // 33.6 MB (attn)
  float2* mlb  = (float2*)(R + 34 * MB);    // 1.05 MB (attn)

  CvtArgs ca;
  ca.src[0] = hs;     ca.dst[0] = hs_b;
  ca.src[1] = q_a_w;  ca.dst[1] = wab;
  ca.src[2] = kv_a_w; ca.dst[2] = wab + (size_t)QLR * H;
  ca.src[3] = q_b_w;  ca.dst[3] = qbw_b;
  ca.src[4] = kv_b_w; ca.dst[4] = kvbw_b;
  ca.src[5] = o_w;    ca.dst[5] = ow_b;
  int sizes4[6] = { SEQ*H/4, QLR*H/4, KVAW_N*H/4, NQH*QLR/4, NKVC*KVLR/4, H*NOV/4 };
  ca.cum[0] = 0;
  for (int i = 0; i < 6; ++i) ca.cum[i+1] = ca.cum[i] + sizes4[i];
  k_cvt_all<<<2048, 256, 0, stream>>>(ca, ca.cum[6]);

  // GEMM1: [qlat | kvlp] = hs @ [q_a_w; kv_a_w]^T  (528 blocks)
  k_gemm64<1><<<dim3(SEQ/128, (QLR + KVAW_N)/64), 256, 0, stream>>>(
      hs_b, wab, qlat, kvlp, QLR + KVAW_N, H);
  // merged rms + rope_k
  k_rms2<<<2*SEQ, 256, 0, stream>>>(qlat, q_a_ln, qlatn, kvlp, kv_a_ln, kvln, kpeb);
  // GEMM2: q_b (fused rope+prescale -> qhm) + kv_b (-> knope, vT)  (896 blocks)
  k_gemm2<<<896, 256, 0, stream>>>(qlatn, qbw_b, kvln, kvbw_b, qhm, knope, vT);
  // attention + combine
  k_attn7<<<640, 256, 0, stream>>>(qhm, knope, kpeb, vT, Opart, mlb);
  k_comb<<<SEQ, 256, 0, stream>>>(Opart, mlb, attnb);
  // GEMM3: out = attn @ o_w^T  (512 blocks)
  k_gemm64<0><<<dim3(SEQ/128, H/64), 256, 0, stream>>>(
      attnb, ow_b, out, nullptr, H, NOV);
}